// Round 2
// baseline (2122.561 us; speedup 1.0000x reference)
//
#include <hip/hip_runtime.h>
#include <hip/hip_bf16.h>
#include <cstdint>

#define B 2
#define N 8192
#define KTOT 17        // self + 16 neighbors
#define CL 64
#define CEF 67         // CL + 3
#define H1 256
#define H2 128
#define CG 1024
#define O1 1024
#define O2 256
#define KMLP 195       // CL + H2 + 3 (global part folded into gvec)
#define NCHUNK 4
#define CHUNK (N / NCHUNK)   // 2048

typedef unsigned long long u64;

__device__ __forceinline__ float lrelu(float v) { return fmaxf(v, 0.01f * v); }

// ---------------- weight transpose: dst[c*O + o] = src[o*stride + off + c] ----------------
__global__ void transpose_w(const float* __restrict__ src, float* __restrict__ dst,
                            int O, int C, int stride, int off) {
    int id = blockIdx.x * 256 + threadIdx.x;
    if (id < O * C) {
        int o = id / C, c = id - o * C;
        dst[c * O + o] = src[o * stride + off + c];
    }
}

// ---------------- gvec[b][o] = b1[o] + W1[o, 0:1024] . global_feat[b] ----------------
__global__ void gvec_kernel(const float* __restrict__ W1, const float* __restrict__ b1,
                            const float* __restrict__ g, float* __restrict__ gvec) {
    int o = blockIdx.x * 256 + threadIdx.x;
    int b = blockIdx.y;
    float s = b1[o];
    const float* row = W1 + (size_t)o * 1219;
    const float* gb = g + b * CG;
    for (int c = 0; c < CG; ++c) s = fmaf(row[c], gb[c], s);
    gvec[b * O1 + o] = s;
}

// ---------------- KNN: per-query top-16 over a candidate chunk ----------------
// key: u64 = (float bits of distance^2) << 32 | candidate index  (exact fp32 compare,
// ties broken by lower index — matches jax.lax.top_k tie behavior on -d^2).
// Score computed with non-contracted ops mirroring the reference formula:
//   pair = (-xx_i) - (-2*dot) - xx_j ;  key = max(-pair, 0)
__global__ __launch_bounds__(256) void knn_chunk_kernel(const float* __restrict__ pts,
                                                        u64* __restrict__ chunkTop) {
    const int t = threadIdx.x;
    const int i = blockIdx.x * 256 + t;
    const int chunk = blockIdx.y;
    const int b = blockIdx.z;
    const float* px = pts + (size_t)b * 3 * N;
    const float* py = px + N;
    const float* pz = py + N;
    const float qx = px[i], qy = py[i], qz = pz[i];
    const float qq = __fadd_rn(__fadd_rn(__fmul_rn(qx, qx), __fmul_rn(qy, qy)),
                               __fmul_rn(qz, qz));
    const float negqq = -qq;
    u64 q[16];
#pragma unroll
    for (int r = 0; r < 16; ++r) q[r] = ~0ull;
    __shared__ float4 cand[256];
    const int base = chunk * CHUNK;
    for (int tile = 0; tile < CHUNK / 256; ++tile) {
        const int j0 = base + tile * 256;
        __syncthreads();
        {
            float cx = px[j0 + t], cy = py[j0 + t], cz = pz[j0 + t];
            float cxx = __fadd_rn(__fadd_rn(__fmul_rn(cx, cx), __fmul_rn(cy, cy)),
                                  __fmul_rn(cz, cz));
            cand[t] = make_float4(cx, cy, cz, cxx);
        }
        __syncthreads();
        for (int s = 0; s < 256; ++s) {
            float4 c = cand[s];
            float dot = __fadd_rn(__fadd_rn(__fmul_rn(qx, c.x), __fmul_rn(qy, c.y)),
                                  __fmul_rn(qz, c.z));
            float inner = __fmul_rn(-2.f, dot);
            float pair = __fsub_rn(__fsub_rn(negqq, inner), c.w);
            float key = fmaxf(-pair, 0.f);
            u64 pk = ((u64)__float_as_uint(key) << 32) | (unsigned)(j0 + s);
            if (j0 + s == i) pk = ~0ull;  // exclude self (re-added in merge)
            if (pk < q[15]) {
#pragma unroll
                for (int r = 15; r >= 1; --r) {
                    u64 sh = (pk > q[r - 1]) ? pk : q[r - 1];  // max
                    q[r] = (pk < q[r]) ? sh : q[r];
                }
                q[0] = (pk < q[0]) ? pk : q[0];
            }
        }
    }
#pragma unroll
    for (int s = 0; s < 16; ++s)
        chunkTop[(size_t)((b * NCHUNK + chunk) * 16 + s) * N + i] = q[s];
}

__global__ __launch_bounds__(256) void knn_merge_kernel(const u64* __restrict__ chunkTop,
                                                        int* __restrict__ idx) {
    const int t = threadIdx.x;
    const int i = blockIdx.x * 256 + t;
    const int b = blockIdx.y;
    u64 q[16];
#pragma unroll
    for (int s = 0; s < 16; ++s)
        q[s] = chunkTop[(size_t)((b * NCHUNK + 0) * 16 + s) * N + i];
    for (int ch = 1; ch < NCHUNK; ++ch) {
#pragma unroll
        for (int s = 0; s < 16; ++s) {
            u64 pk = chunkTop[(size_t)((b * NCHUNK + ch) * 16 + s) * N + i];
            if (pk < q[15]) {
#pragma unroll
                for (int r = 15; r >= 1; --r) {
                    u64 sh = (pk > q[r - 1]) ? pk : q[r - 1];
                    q[r] = (pk < q[r]) ? sh : q[r];
                }
                q[0] = (pk < q[0]) ? pk : q[0];
            } else {
                break;  // chunk list is sorted ascending: rest also fail
            }
        }
    }
    int* op = idx + (size_t)(b * N + i) * KTOT;
    op[0] = i;  // self first
#pragma unroll
    for (int s = 0; s < 16; ++s) op[1 + s] = (int)(q[s] & 8191u);
}

// ---------------- fused edge MLP: gather -> 256x67 -> lrelu -> 128x256 -> max over k ----------------
__global__ __launch_bounds__(256) void ef_mlp_kernel(
        const float* __restrict__ lf, const float* __restrict__ pts,
        const int* __restrict__ idx, const float* __restrict__ Wt1,
        const float* __restrict__ bias1, const float* __restrict__ Wt2,
        const float* __restrict__ bias2, float* __restrict__ fmax_out) {
    const int t = threadIdx.x;
    const int n = blockIdx.x;
    const int b = blockIdx.y;
    __shared__ int idx_l[KTOT];
    __shared__ float f_l[CEF * KTOT];
    __shared__ float h1_l[H1 * KTOT];
    __shared__ float pm[2 * H2];
    if (t < KTOT) idx_l[t] = idx[(size_t)(b * N + n) * KTOT + t];
    __syncthreads();
    for (int e = t; e < CEF * KTOT; e += 256) {
        int c = e / KTOT, k = e - c * KTOT;
        float v;
        if (c < CL) {
            v = lf[(size_t)(b * CL + c) * N + idx_l[k]];
        } else {
            int d = c - CL;
            float self = pts[(size_t)(b * 3 + d) * N + n];
            v = (k == 0) ? self : self - pts[(size_t)(b * 3 + d) * N + idx_l[k]];
        }
        f_l[c * KTOT + k] = v;
    }
    __syncthreads();
    // h1: one output channel per thread (o = t), 17 k-slots in registers
    float acc[KTOT];
#pragma unroll
    for (int k = 0; k < KTOT; ++k) acc[k] = 0.f;
    for (int c = 0; c < CEF; ++c) {
        float w = Wt1[c * H1 + t];
#pragma unroll
        for (int k = 0; k < KTOT; ++k) acc[k] = fmaf(w, f_l[c * KTOT + k], acc[k]);
    }
    float bb = bias1[t];
#pragma unroll
    for (int k = 0; k < KTOT; ++k) h1_l[t * KTOT + k] = lrelu(acc[k] + bb);
    __syncthreads();
    // h2: o = t&127, two k-halves (k=8 computed twice; harmless under max)
    const int o = t & (H2 - 1);
    const int g = t >> 7;
    const int kb = g * 8;
    float a2[9];
#pragma unroll
    for (int k = 0; k < 9; ++k) a2[k] = 0.f;
    for (int c = 0; c < H1; ++c) {
        float w = Wt2[c * H2 + o];
#pragma unroll
        for (int k = 0; k < 9; ++k) a2[k] = fmaf(w, h1_l[c * KTOT + kb + k], a2[k]);
    }
    float b2b = bias2[o];
    float m = a2[0] + b2b;
#pragma unroll
    for (int k = 1; k < 9; ++k) m = fmaxf(m, a2[k] + b2b);
    pm[g * H2 + o] = m;
    __syncthreads();
    if (t < H2) {
        float fm = fmaxf(pm[t], pm[H2 + t]);
        fmax_out[(size_t)(b * N + n) * H2 + t] = fm;  // layout [B][N][128] for coalesced reuse
    }
}

// ---------------- fused final MLP: feat(195) -> 1024 -> lrelu -> 256 -> lrelu -> 1 ----------------
__global__ __launch_bounds__(256) void mlp_kernel(
        const float* __restrict__ lf, const float* __restrict__ pts,
        const float* __restrict__ fmax_in, const float* __restrict__ gvec,
        const float* __restrict__ W1t, const float* __restrict__ W2t,
        const float* __restrict__ W3, const float* __restrict__ b2v,
        const float* __restrict__ b3v, float* __restrict__ out) {
    const int t = threadIdx.x;
    const int n0 = blockIdx.x * 16;
    const int b = blockIdx.y;
    __shared__ float feat[KMLP * 17];   // stride 17 to avoid bank conflicts
    __shared__ float y1c[256 * 17];     // one 256-chunk of y1 at a time
    __shared__ float y2s[O2 * 17];
    __shared__ float red[256];
    // stage features for 16 points
    {
        int e = t;
#pragma unroll
        for (int it = 0; it < 4; ++it, e += 256) {  // local feats 64x16
            int c = e >> 4, p = e & 15;
            feat[c * 17 + p] = lf[(size_t)(b * CL + c) * N + n0 + p];
        }
        e = t;
#pragma unroll
        for (int it = 0; it < 8; ++it, e += 256) {  // fmax 128x16
            int cc = e & 127, pp = e >> 7;
            feat[(CL + cc) * 17 + pp] = fmax_in[(size_t)(b * N + n0 + pp) * H2 + cc];
        }
        if (t < 48) {  // xyz 3x16
            int d = t >> 4, p = t & 15;
            feat[(CL + H2 + d) * 17 + p] = pts[(size_t)(b * 3 + d) * N + n0 + p];
        }
    }
    __syncthreads();
    float a2[16];
#pragma unroll
    for (int p = 0; p < 16; ++p) a2[p] = 0.f;
    for (int chunk = 0; chunk < 4; ++chunk) {
        const int o = chunk * 256 + t;
        float acc[16];
#pragma unroll
        for (int p = 0; p < 16; ++p) acc[p] = 0.f;
        for (int c = 0; c < KMLP; ++c) {
            float w = W1t[(size_t)c * O1 + o];
#pragma unroll
            for (int p = 0; p < 16; ++p) acc[p] = fmaf(w, feat[c * 17 + p], acc[p]);
        }
        float gb = gvec[b * O1 + o];  // includes b1
        if (chunk) __syncthreads();   // previous chunk's readers must finish
#pragma unroll
        for (int p = 0; p < 16; ++p) y1c[t * 17 + p] = lrelu(acc[p] + gb);
        __syncthreads();
        for (int c = 0; c < 256; ++c) {
            float w = W2t[(size_t)(chunk * 256 + c) * O2 + t];
#pragma unroll
            for (int p = 0; p < 16; ++p) a2[p] = fmaf(w, y1c[c * 17 + p], a2[p]);
        }
    }
    float bb = b2v[t];
#pragma unroll
    for (int p = 0; p < 16; ++p) y2s[t * 17 + p] = lrelu(a2[p] + bb);
    __syncthreads();
    {
        const int p = t & 15, seg = t >> 4;
        float part = 0.f;
#pragma unroll
        for (int oo = 0; oo < 16; ++oo)
            part = fmaf(W3[seg * 16 + oo], y2s[(seg * 16 + oo) * 17 + p], part);
        red[t] = part;  // t == seg*16 + p
    }
    __syncthreads();
    if (t < 16) {
        float s = b3v[0];
#pragma unroll
        for (int seg = 0; seg < 16; ++seg) s += red[seg * 16 + t];
        out[(size_t)b * N + n0 + t] = s;
    }
}

extern "C" void kernel_launch(void* const* d_in, const int* in_sizes, int n_in,
                              void* d_out, int out_size, void* d_ws, size_t ws_size,
                              hipStream_t stream) {
    const float* g     = (const float*)d_in[0];
    const float* pts   = (const float*)d_in[1];
    const float* lf    = (const float*)d_in[2];
    const float* W_ef1 = (const float*)d_in[3];
    const float* b_ef1 = (const float*)d_in[4];
    const float* W_ef2 = (const float*)d_in[5];
    const float* b_ef2 = (const float*)d_in[6];
    const float* W1    = (const float*)d_in[7];
    const float* b1    = (const float*)d_in[8];
    const float* W2    = (const float*)d_in[9];
    const float* b2    = (const float*)d_in[10];
    const float* W3    = (const float*)d_in[11];
    const float* b3    = (const float*)d_in[12];
    float* out = (float*)d_out;

    char* ws = (char*)d_ws;
    int*      idx      = (int*)ws;      ws += (size_t)B * N * KTOT * 4;
    u64*      chunkTop = (u64*)ws;      ws += (size_t)B * NCHUNK * 16 * N * 8;
    float*    fmax_ws  = (float*)ws;    ws += (size_t)B * N * H2 * 4;
    float*    gvec     = (float*)ws;    ws += (size_t)B * O1 * 4;
    float*    W1t      = (float*)ws;    ws += (size_t)KMLP * O1 * 4;
    float*    W2t      = (float*)ws;    ws += (size_t)O1 * O2 * 4;
    float*    Wef1t    = (float*)ws;    ws += (size_t)CEF * H1 * 4;
    float*    Wef2t    = (float*)ws;    ws += (size_t)H1 * H2 * 4;

    transpose_w<<<dim3((CEF * H1 + 255) / 256), 256, 0, stream>>>(W_ef1, Wef1t, H1, CEF, CEF, 0);
    transpose_w<<<dim3((H1 * H2 + 255) / 256), 256, 0, stream>>>(W_ef2, Wef2t, H2, H1, H1, 0);
    transpose_w<<<dim3((KMLP * O1 + 255) / 256), 256, 0, stream>>>(W1, W1t, O1, KMLP, 1219, 1024);
    transpose_w<<<dim3((O1 * O2 + 255) / 256), 256, 0, stream>>>(W2, W2t, O2, O1, O1, 0);
    gvec_kernel<<<dim3(O1 / 256, B), 256, 0, stream>>>(W1, b1, g, gvec);
    knn_chunk_kernel<<<dim3(N / 256, NCHUNK, B), 256, 0, stream>>>(pts, chunkTop);
    knn_merge_kernel<<<dim3(N / 256, B), 256, 0, stream>>>(chunkTop, idx);
    ef_mlp_kernel<<<dim3(N, B), 256, 0, stream>>>(lf, pts, idx, Wef1t, b_ef1, Wef2t, b_ef2, fmax_ws);
    mlp_kernel<<<dim3(N / 16, B), 256, 0, stream>>>(lf, pts, fmax_ws, gvec, W1t, W2t, W3, b2, b3, out);
}

// Round 3
// 1367.969 us; speedup vs baseline: 1.5516x; 1.5516x over previous
//
#include <hip/hip_runtime.h>
#include <hip/hip_bf16.h>
#include <cstdint>

#define B 2
#define N 8192
#define KTOT 17        // self + 16 neighbors
#define CL 64
#define CEF 67         // CL + 3
#define H1 256
#define H2 128
#define CG 1024
#define O1 1024
#define O2 256
#define KMLP 195       // CL + H2 + 3 (global part folded into gvec)
#define NCHUNK 16
#define CHUNK (N / NCHUNK)   // 512

typedef unsigned long long u64;

__device__ __forceinline__ float lrelu(float v) { return fmaxf(v, 0.01f * v); }

// ---------------- weight transpose: dst[c*O + o] = src[o*stride + off + c] ----------------
__global__ void transpose_w(const float* __restrict__ src, float* __restrict__ dst,
                            int O, int C, int stride, int off) {
    int id = blockIdx.x * 256 + threadIdx.x;
    if (id < O * C) {
        int o = id / C, c = id - o * C;
        dst[c * O + o] = src[o * stride + off + c];
    }
}

// ---------------- gvec[b][o] = b1[o] + W1[o, 0:1024] . global_feat[b] ----------------
__global__ void gvec_kernel(const float* __restrict__ W1, const float* __restrict__ b1,
                            const float* __restrict__ g, float* __restrict__ gvec) {
    int o = blockIdx.x * 256 + threadIdx.x;
    int b = blockIdx.y;
    float s = b1[o];
    const float* row = W1 + (size_t)o * 1219;
    const float* gb = g + b * CG;
    for (int c = 0; c < CG; ++c) s = fmaf(row[c], gb[c], s);
    gvec[b * O1 + o] = s;
}

// ---------------- KNN pass1: per (query, chunk) sorted 16 smallest DISTANCES (value-only) ----------------
// key = fp32 bits of max(d^2, 0), computed with non-contracted ops mirroring the
// reference formula so ordering tracks the numpy reference to ~1 ulp.
// Branch-free sorted insert: qd[r] = min(max(pk, qd[r-1]), qd[r])  (clamp == median).
__global__ __launch_bounds__(256) void knn_pass1(const float* __restrict__ pts,
                                                 unsigned* __restrict__ topd) {
    const int t = threadIdx.x;
    const int i = blockIdx.x * 256 + t;
    const int chunk = blockIdx.y;
    const int b = blockIdx.z;
    const float* px = pts + (size_t)b * 3 * N;
    const float* py = px + N;
    const float* pz = py + N;
    const float qx = px[i], qy = py[i], qz = pz[i];
    const float qq = __fadd_rn(__fadd_rn(__fmul_rn(qx, qx), __fmul_rn(qy, qy)),
                               __fmul_rn(qz, qz));
    const float negqq = -qq;
    unsigned qd[16];
#pragma unroll
    for (int r = 0; r < 16; ++r) qd[r] = 0xFFFFFFFFu;
    __shared__ float4 cand[256];
    const int base = chunk * CHUNK;
    for (int tile = 0; tile < CHUNK / 256; ++tile) {
        const int j0 = base + tile * 256;
        __syncthreads();
        {
            float cx = px[j0 + t], cy = py[j0 + t], cz = pz[j0 + t];
            float cxx = __fadd_rn(__fadd_rn(__fmul_rn(cx, cx), __fmul_rn(cy, cy)),
                                  __fmul_rn(cz, cz));
            cand[t] = make_float4(cx, cy, cz, cxx);
        }
        __syncthreads();
#pragma unroll 4
        for (int s = 0; s < 256; ++s) {
            float4 c = cand[s];
            float dot = __fadd_rn(__fadd_rn(__fmul_rn(qx, c.x), __fmul_rn(qy, c.y)),
                                  __fmul_rn(qz, c.z));
            float inner = __fmul_rn(-2.f, dot);
            float pair = __fsub_rn(__fsub_rn(negqq, inner), c.w);
            float key = fmaxf(-pair, 0.f);
            unsigned pk = __float_as_uint(key);
            if (j0 + s == i) pk = 0xFFFFFFFFu;  // exclude self
#pragma unroll
            for (int r = 15; r >= 1; --r) {
                unsigned hi = pk > qd[r - 1] ? pk : qd[r - 1];  // v_max_u32
                qd[r] = hi < qd[r] ? hi : qd[r];                // v_min_u32
            }
            qd[0] = pk < qd[0] ? pk : qd[0];
        }
    }
#pragma unroll
    for (int s = 0; s < 16; ++s)
        topd[(size_t)((b * NCHUNK + chunk) * 16 + s) * N + i] = qd[s];
}

// ---------------- KNN thresh: merge chunk lists -> global 16th smallest distance T ----------------
__global__ __launch_bounds__(256) void knn_thresh(const unsigned* __restrict__ topd,
                                                  unsigned* __restrict__ Tbuf) {
    const int t = threadIdx.x;
    const int i = blockIdx.x * 256 + t;
    const int b = blockIdx.y;
    unsigned qd[16];
#pragma unroll
    for (int s = 0; s < 16; ++s)
        qd[s] = topd[(size_t)((b * NCHUNK + 0) * 16 + s) * N + i];
    for (int c = 1; c < NCHUNK; ++c) {
        for (int s = 0; s < 16; ++s) {
            unsigned pk = topd[(size_t)((b * NCHUNK + c) * 16 + s) * N + i];
            if (pk >= qd[15]) break;  // sorted: rest of chunk also fails
#pragma unroll
            for (int r = 15; r >= 1; --r) {
                unsigned hi = pk > qd[r - 1] ? pk : qd[r - 1];
                qd[r] = hi < qd[r] ? hi : qd[r];
            }
            qd[0] = pk < qd[0] ? pk : qd[0];
        }
    }
    Tbuf[b * N + i] = qd[15];
}

// ---------------- KNN recover: rescan, collect indices with d<T (+ d==T ties, lowest-index) ----------------
// 16 lanes per query; order within the 16 output slots is irrelevant downstream (max over k).
__global__ __launch_bounds__(256) void knn_recover(const float* __restrict__ pts,
                                                   const unsigned* __restrict__ Tbuf,
                                                   int* __restrict__ idx) {
    const int t = threadIdx.x;
    const int lg = t & 15;   // lane in group
    const int grp = t >> 4;  // 16 groups per block
    const int b = blockIdx.y;
    const int gq = blockIdx.x * 16 + grp;
    const float* px = pts + (size_t)b * 3 * N;
    const float* py = px + N;
    const float* pz = py + N;
    __shared__ float4 cand[256];
    __shared__ unsigned sbuf[16][16];
    __shared__ unsigned tbuf[16][32];
    __shared__ int scnt[16], tcnt[16];
    if (t < 16) { scnt[t] = 0; tcnt[t] = 0; }
    const float qx = px[gq], qy = py[gq], qz = pz[gq];
    const float qq = __fadd_rn(__fadd_rn(__fmul_rn(qx, qx), __fmul_rn(qy, qy)),
                               __fmul_rn(qz, qz));
    const float negqq = -qq;
    const unsigned T = Tbuf[b * N + gq];
    for (int tile = 0; tile < N / 256; ++tile) {
        const int j0 = tile * 256;
        __syncthreads();
        {
            float cx = px[j0 + t], cy = py[j0 + t], cz = pz[j0 + t];
            float cxx = __fadd_rn(__fadd_rn(__fmul_rn(cx, cx), __fmul_rn(cy, cy)),
                                  __fmul_rn(cz, cz));
            cand[t] = make_float4(cx, cy, cz, cxx);
        }
        __syncthreads();
        for (int it = 0; it < 16; ++it) {
            int s = it * 16 + lg;
            float4 c = cand[s];
            float dot = __fadd_rn(__fadd_rn(__fmul_rn(qx, c.x), __fmul_rn(qy, c.y)),
                                  __fmul_rn(qz, c.z));
            float inner = __fmul_rn(-2.f, dot);
            float pair = __fsub_rn(__fsub_rn(negqq, inner), c.w);
            float key = fmaxf(-pair, 0.f);
            unsigned pk = __float_as_uint(key);
            int j = j0 + s;
            bool hit = (j != gq) && (pk <= T);
            if (__any(hit)) {
                if (hit) {
                    if (pk < T) {
                        int p = atomicAdd(&scnt[grp], 1);
                        if (p < 16) sbuf[grp][p] = (unsigned)j;
                    } else {
                        int p = atomicAdd(&tcnt[grp], 1);
                        if (p < 32) tbuf[grp][p] = (unsigned)j;
                    }
                }
            }
        }
    }
    __syncthreads();
    int s_cnt = scnt[grp];
    int t_cnt = tcnt[grp]; if (t_cnt > 32) t_cnt = 32;
    int need = 16 - s_cnt;
    if (t_cnt > need && lg == 0) {  // rare: sort ties ascending by index
        for (int a = 1; a < t_cnt; ++a) {
            unsigned v = tbuf[grp][a]; int bq = a;
            while (bq > 0 && tbuf[grp][bq - 1] > v) { tbuf[grp][bq] = tbuf[grp][bq - 1]; --bq; }
            tbuf[grp][bq] = v;
        }
    }
    __syncthreads();
    int* op = idx + (size_t)(b * N + gq) * KTOT;
    if (lg == 0) op[0] = gq;
    unsigned e = (unsigned)gq;
    if (lg < s_cnt) e = sbuf[grp][lg];
    else if (lg - s_cnt < t_cnt) e = tbuf[grp][lg - s_cnt];
    op[1 + lg] = (int)e;
}

// ---------------- fused edge MLP: gather -> 256x67 -> lrelu -> 128x256 -> max over k ----------------
__global__ __launch_bounds__(256) void ef_mlp_kernel(
        const float* __restrict__ lf, const float* __restrict__ pts,
        const int* __restrict__ idx, const float* __restrict__ Wt1,
        const float* __restrict__ bias1, const float* __restrict__ Wt2,
        const float* __restrict__ bias2, float* __restrict__ fmax_out) {
    const int t = threadIdx.x;
    const int n = blockIdx.x;
    const int b = blockIdx.y;
    __shared__ int idx_l[KTOT];
    __shared__ float f_l[CEF * KTOT];
    __shared__ float h1_l[H1 * KTOT];
    __shared__ float pm[2 * H2];
    if (t < KTOT) idx_l[t] = idx[(size_t)(b * N + n) * KTOT + t];
    __syncthreads();
    for (int e = t; e < CEF * KTOT; e += 256) {
        int c = e / KTOT, k = e - c * KTOT;
        float v;
        if (c < CL) {
            v = lf[(size_t)(b * CL + c) * N + idx_l[k]];
        } else {
            int d = c - CL;
            float self = pts[(size_t)(b * 3 + d) * N + n];
            v = (k == 0) ? self : self - pts[(size_t)(b * 3 + d) * N + idx_l[k]];
        }
        f_l[c * KTOT + k] = v;
    }
    __syncthreads();
    float acc[KTOT];
#pragma unroll
    for (int k = 0; k < KTOT; ++k) acc[k] = 0.f;
    for (int c = 0; c < CEF; ++c) {
        float w = Wt1[c * H1 + t];
#pragma unroll
        for (int k = 0; k < KTOT; ++k) acc[k] = fmaf(w, f_l[c * KTOT + k], acc[k]);
    }
    float bb = bias1[t];
#pragma unroll
    for (int k = 0; k < KTOT; ++k) h1_l[t * KTOT + k] = lrelu(acc[k] + bb);
    __syncthreads();
    const int o = t & (H2 - 1);
    const int g = t >> 7;
    const int kb = g * 8;
    float a2[9];
#pragma unroll
    for (int k = 0; k < 9; ++k) a2[k] = 0.f;
    for (int c = 0; c < H1; ++c) {
        float w = Wt2[c * H2 + o];
#pragma unroll
        for (int k = 0; k < 9; ++k) a2[k] = fmaf(w, h1_l[c * KTOT + kb + k], a2[k]);
    }
    float b2b = bias2[o];
    float m = a2[0] + b2b;
#pragma unroll
    for (int k = 1; k < 9; ++k) m = fmaxf(m, a2[k] + b2b);
    pm[g * H2 + o] = m;
    __syncthreads();
    if (t < H2) {
        float fm = fmaxf(pm[t], pm[H2 + t]);
        fmax_out[(size_t)(b * N + n) * H2 + t] = fm;
    }
}

// ---------------- fused final MLP: feat(195) -> 1024 -> lrelu -> 256 -> lrelu -> 1 ----------------
__global__ __launch_bounds__(256) void mlp_kernel(
        const float* __restrict__ lf, const float* __restrict__ pts,
        const float* __restrict__ fmax_in, const float* __restrict__ gvec,
        const float* __restrict__ W1t, const float* __restrict__ W2t,
        const float* __restrict__ W3, const float* __restrict__ b2v,
        const float* __restrict__ b3v, float* __restrict__ out) {
    const int t = threadIdx.x;
    const int n0 = blockIdx.x * 16;
    const int b = blockIdx.y;
    __shared__ float feat[KMLP * 17];
    __shared__ float y1c[256 * 17];
    __shared__ float y2s[O2 * 17];
    __shared__ float red[256];
    {
        int e = t;
#pragma unroll
        for (int it = 0; it < 4; ++it, e += 256) {
            int c = e >> 4, p = e & 15;
            feat[c * 17 + p] = lf[(size_t)(b * CL + c) * N + n0 + p];
        }
        e = t;
#pragma unroll
        for (int it = 0; it < 8; ++it, e += 256) {
            int cc = e & 127, pp = e >> 7;
            feat[(CL + cc) * 17 + pp] = fmax_in[(size_t)(b * N + n0 + pp) * H2 + cc];
        }
        if (t < 48) {
            int d = t >> 4, p = t & 15;
            feat[(CL + H2 + d) * 17 + p] = pts[(size_t)(b * 3 + d) * N + n0 + p];
        }
    }
    __syncthreads();
    float a2[16];
#pragma unroll
    for (int p = 0; p < 16; ++p) a2[p] = 0.f;
    for (int chunk = 0; chunk < 4; ++chunk) {
        const int o = chunk * 256 + t;
        float acc[16];
#pragma unroll
        for (int p = 0; p < 16; ++p) acc[p] = 0.f;
        for (int c = 0; c < KMLP; ++c) {
            float w = W1t[(size_t)c * O1 + o];
#pragma unroll
            for (int p = 0; p < 16; ++p) acc[p] = fmaf(w, feat[c * 17 + p], acc[p]);
        }
        float gb = gvec[b * O1 + o];
        if (chunk) __syncthreads();
#pragma unroll
        for (int p = 0; p < 16; ++p) y1c[t * 17 + p] = lrelu(acc[p] + gb);
        __syncthreads();
        for (int c = 0; c < 256; ++c) {
            float w = W2t[(size_t)(chunk * 256 + c) * O2 + t];
#pragma unroll
            for (int p = 0; p < 16; ++p) a2[p] = fmaf(w, y1c[c * 17 + p], a2[p]);
        }
    }
    float bb = b2v[t];
#pragma unroll
    for (int p = 0; p < 16; ++p) y2s[t * 17 + p] = lrelu(a2[p] + bb);
    __syncthreads();
    {
        const int p = t & 15, seg = t >> 4;
        float part = 0.f;
#pragma unroll
        for (int oo = 0; oo < 16; ++oo)
            part = fmaf(W3[seg * 16 + oo], y2s[(seg * 16 + oo) * 17 + p], part);
        red[t] = part;
    }
    __syncthreads();
    if (t < 16) {
        float s = b3v[0];
#pragma unroll
        for (int seg = 0; seg < 16; ++seg) s += red[seg * 16 + t];
        out[(size_t)b * N + n0 + t] = s;
    }
}

extern "C" void kernel_launch(void* const* d_in, const int* in_sizes, int n_in,
                              void* d_out, int out_size, void* d_ws, size_t ws_size,
                              hipStream_t stream) {
    const float* g     = (const float*)d_in[0];
    const float* pts   = (const float*)d_in[1];
    const float* lf    = (const float*)d_in[2];
    const float* W_ef1 = (const float*)d_in[3];
    const float* b_ef1 = (const float*)d_in[4];
    const float* W_ef2 = (const float*)d_in[5];
    const float* b_ef2 = (const float*)d_in[6];
    const float* W1    = (const float*)d_in[7];
    const float* b1    = (const float*)d_in[8];
    const float* W2    = (const float*)d_in[9];
    const float* b2    = (const float*)d_in[10];
    const float* W3    = (const float*)d_in[11];
    const float* b3    = (const float*)d_in[12];
    float* out = (float*)d_out;

    char* ws = (char*)d_ws;
    int*      idx   = (int*)ws;      ws += (size_t)B * N * KTOT * 4;
    unsigned* topd  = (unsigned*)ws;
    float*    fmax_ws = (float*)topd;   // alias: topd dead before ef_mlp writes fmax
    ws += (size_t)B * NCHUNK * 16 * N * 4;
    unsigned* Tbuf  = (unsigned*)ws; ws += (size_t)B * N * 4;
    float*    gvec  = (float*)ws;    ws += (size_t)B * O1 * 4;
    float*    W1t   = (float*)ws;    ws += (size_t)KMLP * O1 * 4;
    float*    W2t   = (float*)ws;    ws += (size_t)O1 * O2 * 4;
    float*    Wef1t = (float*)ws;    ws += (size_t)CEF * H1 * 4;
    float*    Wef2t = (float*)ws;    ws += (size_t)H1 * H2 * 4;

    transpose_w<<<dim3((CEF * H1 + 255) / 256), 256, 0, stream>>>(W_ef1, Wef1t, H1, CEF, CEF, 0);
    transpose_w<<<dim3((H1 * H2 + 255) / 256), 256, 0, stream>>>(W_ef2, Wef2t, H2, H1, H1, 0);
    transpose_w<<<dim3((KMLP * O1 + 255) / 256), 256, 0, stream>>>(W1, W1t, O1, KMLP, 1219, 1024);
    transpose_w<<<dim3((O1 * O2 + 255) / 256), 256, 0, stream>>>(W2, W2t, O2, O1, O1, 0);
    gvec_kernel<<<dim3(O1 / 256, B), 256, 0, stream>>>(W1, b1, g, gvec);
    knn_pass1<<<dim3(N / 256, NCHUNK, B), 256, 0, stream>>>(pts, topd);
    knn_thresh<<<dim3(N / 256, B), 256, 0, stream>>>(topd, Tbuf);
    knn_recover<<<dim3(N / 16, B), 256, 0, stream>>>(pts, Tbuf, idx);
    ef_mlp_kernel<<<dim3(N, B), 256, 0, stream>>>(lf, pts, idx, Wef1t, b_ef1, Wef2t, b_ef2, fmax_ws);
    mlp_kernel<<<dim3(N / 16, B), 256, 0, stream>>>(lf, pts, fmax_ws, gvec, W1t, W2t, W3, b2, b3, out);
}

// Round 4
// 747.899 us; speedup vs baseline: 2.8380x; 1.8291x over previous
//
#include <hip/hip_runtime.h>
#include <hip/hip_bf16.h>
#include <cstdint>

#define B 2
#define N 8192
#define KTOT 17        // self + 16 neighbors
#define CL 64
#define CEF 67         // CL + 3
#define H1 256
#define H2 128
#define CG 1024
#define O1 1024
#define O2 256
#define KMLP 195       // CL + H2 + 3 (global part folded into gvec)
#define NCHUNK 16
#define CHUNK (N / NCHUNK)   // 512

typedef unsigned long long u64;
typedef __bf16 bf16x8 __attribute__((ext_vector_type(8)));
typedef float f32x4 __attribute__((ext_vector_type(4)));

__device__ __forceinline__ float lrelu(float v) { return fmaxf(v, 0.01f * v); }

__device__ __forceinline__ unsigned short f2bf(float f) {  // RNE
    union { float f; unsigned u; } v; v.f = f;
    unsigned r = v.u + 0x7FFFu + ((v.u >> 16) & 1u);
    return (unsigned short)(r >> 16);
}

// ---------------- weight transpose: dst[c*O + o] = src[o*stride + off + c] ----------------
__global__ void transpose_w(const float* __restrict__ src, float* __restrict__ dst,
                            int O, int C, int stride, int off) {
    int id = blockIdx.x * 256 + threadIdx.x;
    if (id < O * C) {
        int o = id / C, c = id - o * C;
        dst[c * O + o] = src[o * stride + off + c];
    }
}

// ---------------- prepack ef weights into MFMA fragment order (bf16) ----------------
// layout: [mtile][kstep][lane][8] ; element (m,k): m = mt*16+(l&15), k = ks*32+(l>>4)*8+j
__global__ void prepack_w1(const float* __restrict__ W, unsigned short* __restrict__ out) {
    int id = blockIdx.x * 256 + threadIdx.x;          // 16*3*512 = 24576
    if (id >= 16 * 3 * 512) return;
    int j = id & 7, l = (id >> 3) & 63, rest = id >> 9;
    int ks = rest % 3, mt = rest / 3;
    int m = mt * 16 + (l & 15);
    int k = ks * 32 + ((l >> 4) << 3) + j;
    float v = (k < CEF) ? W[m * CEF + k] : 0.f;
    out[id] = f2bf(v);
}
__global__ void prepack_w2(const float* __restrict__ W, unsigned short* __restrict__ out) {
    int id = blockIdx.x * 256 + threadIdx.x;          // 8*8*512 = 32768
    if (id >= 8 * 8 * 512) return;
    int j = id & 7, l = (id >> 3) & 63, rest = id >> 9;
    int ks = rest & 7, mt = rest >> 3;
    int m = mt * 16 + (l & 15);
    int k = ks * 32 + ((l >> 4) << 3) + j;
    out[id] = f2bf(W[m * H1 + k]);
}

// ---------------- gvec[b][o] = b1[o] + W1[o, 0:1024] . global_feat[b] ----------------
__global__ void gvec_kernel(const float* __restrict__ W1, const float* __restrict__ b1,
                            const float* __restrict__ g, float* __restrict__ gvec) {
    int o = blockIdx.x * 256 + threadIdx.x;
    int b = blockIdx.y;
    float s = b1[o];
    const float* row = W1 + (size_t)o * 1219;
    const float* gb = g + b * CG;
    for (int c = 0; c < CG; ++c) s = fmaf(row[c], gb[c], s);
    gvec[b * O1 + o] = s;
}

// ---------------- KNN pass1 ----------------
__global__ __launch_bounds__(256) void knn_pass1(const float* __restrict__ pts,
                                                 unsigned* __restrict__ topd) {
    const int t = threadIdx.x;
    const int i = blockIdx.x * 256 + t;
    const int chunk = blockIdx.y;
    const int b = blockIdx.z;
    const float* px = pts + (size_t)b * 3 * N;
    const float* py = px + N;
    const float* pz = py + N;
    const float qx = px[i], qy = py[i], qz = pz[i];
    const float qq = __fadd_rn(__fadd_rn(__fmul_rn(qx, qx), __fmul_rn(qy, qy)),
                               __fmul_rn(qz, qz));
    const float negqq = -qq;
    unsigned qd[16];
#pragma unroll
    for (int r = 0; r < 16; ++r) qd[r] = 0xFFFFFFFFu;
    __shared__ float4 cand[256];
    const int base = chunk * CHUNK;
    for (int tile = 0; tile < CHUNK / 256; ++tile) {
        const int j0 = base + tile * 256;
        __syncthreads();
        {
            float cx = px[j0 + t], cy = py[j0 + t], cz = pz[j0 + t];
            float cxx = __fadd_rn(__fadd_rn(__fmul_rn(cx, cx), __fmul_rn(cy, cy)),
                                  __fmul_rn(cz, cz));
            cand[t] = make_float4(cx, cy, cz, cxx);
        }
        __syncthreads();
#pragma unroll 4
        for (int s = 0; s < 256; ++s) {
            float4 c = cand[s];
            float dot = __fadd_rn(__fadd_rn(__fmul_rn(qx, c.x), __fmul_rn(qy, c.y)),
                                  __fmul_rn(qz, c.z));
            float inner = __fmul_rn(-2.f, dot);
            float pair = __fsub_rn(__fsub_rn(negqq, inner), c.w);
            float key = fmaxf(-pair, 0.f);
            unsigned pk = __float_as_uint(key);
            if (j0 + s == i) pk = 0xFFFFFFFFu;  // exclude self
#pragma unroll
            for (int r = 15; r >= 1; --r) {
                unsigned hi = pk > qd[r - 1] ? pk : qd[r - 1];
                qd[r] = hi < qd[r] ? hi : qd[r];
            }
            qd[0] = pk < qd[0] ? pk : qd[0];
        }
    }
#pragma unroll
    for (int s = 0; s < 16; ++s)
        topd[(size_t)((b * NCHUNK + chunk) * 16 + s) * N + i] = qd[s];
}

// ---------------- KNN thresh ----------------
__global__ __launch_bounds__(256) void knn_thresh(const unsigned* __restrict__ topd,
                                                  unsigned* __restrict__ Tbuf) {
    const int t = threadIdx.x;
    const int i = blockIdx.x * 256 + t;
    const int b = blockIdx.y;
    unsigned qd[16];
#pragma unroll
    for (int s = 0; s < 16; ++s)
        qd[s] = topd[(size_t)((b * NCHUNK + 0) * 16 + s) * N + i];
    for (int c = 1; c < NCHUNK; ++c) {
        for (int s = 0; s < 16; ++s) {
            unsigned pk = topd[(size_t)((b * NCHUNK + c) * 16 + s) * N + i];
            if (pk >= qd[15]) break;
#pragma unroll
            for (int r = 15; r >= 1; --r) {
                unsigned hi = pk > qd[r - 1] ? pk : qd[r - 1];
                qd[r] = hi < qd[r] ? hi : qd[r];
            }
            qd[0] = pk < qd[0] ? pk : qd[0];
        }
    }
    Tbuf[b * N + i] = qd[15];
}

// ---------------- KNN recover ----------------
__global__ __launch_bounds__(256) void knn_recover(const float* __restrict__ pts,
                                                   const unsigned* __restrict__ Tbuf,
                                                   int* __restrict__ idx) {
    const int t = threadIdx.x;
    const int lg = t & 15;
    const int grp = t >> 4;
    const int b = blockIdx.y;
    const int gq = blockIdx.x * 16 + grp;
    const float* px = pts + (size_t)b * 3 * N;
    const float* py = px + N;
    const float* pz = py + N;
    __shared__ float4 cand[256];
    __shared__ unsigned sbuf[16][16];
    __shared__ unsigned tbuf[16][32];
    __shared__ int scnt[16], tcnt[16];
    if (t < 16) { scnt[t] = 0; tcnt[t] = 0; }
    const float qx = px[gq], qy = py[gq], qz = pz[gq];
    const float qq = __fadd_rn(__fadd_rn(__fmul_rn(qx, qx), __fmul_rn(qy, qy)),
                               __fmul_rn(qz, qz));
    const float negqq = -qq;
    const unsigned T = Tbuf[b * N + gq];
    for (int tile = 0; tile < N / 256; ++tile) {
        const int j0 = tile * 256;
        __syncthreads();
        {
            float cx = px[j0 + t], cy = py[j0 + t], cz = pz[j0 + t];
            float cxx = __fadd_rn(__fadd_rn(__fmul_rn(cx, cx), __fmul_rn(cy, cy)),
                                  __fmul_rn(cz, cz));
            cand[t] = make_float4(cx, cy, cz, cxx);
        }
        __syncthreads();
        for (int it = 0; it < 16; ++it) {
            int s = it * 16 + lg;
            float4 c = cand[s];
            float dot = __fadd_rn(__fadd_rn(__fmul_rn(qx, c.x), __fmul_rn(qy, c.y)),
                                  __fmul_rn(qz, c.z));
            float inner = __fmul_rn(-2.f, dot);
            float pair = __fsub_rn(__fsub_rn(negqq, inner), c.w);
            float key = fmaxf(-pair, 0.f);
            unsigned pk = __float_as_uint(key);
            int j = j0 + s;
            bool hit = (j != gq) && (pk <= T);
            if (__any(hit)) {
                if (hit) {
                    if (pk < T) {
                        int p = atomicAdd(&scnt[grp], 1);
                        if (p < 16) sbuf[grp][p] = (unsigned)j;
                    } else {
                        int p = atomicAdd(&tcnt[grp], 1);
                        if (p < 32) tbuf[grp][p] = (unsigned)j;
                    }
                }
            }
        }
    }
    __syncthreads();
    int s_cnt = scnt[grp];
    int t_cnt = tcnt[grp]; if (t_cnt > 32) t_cnt = 32;
    int need = 16 - s_cnt;
    if (t_cnt > need && lg == 0) {
        for (int a = 1; a < t_cnt; ++a) {
            unsigned v = tbuf[grp][a]; int bq = a;
            while (bq > 0 && tbuf[grp][bq - 1] > v) { tbuf[grp][bq] = tbuf[grp][bq - 1]; --bq; }
            tbuf[grp][bq] = v;
        }
    }
    __syncthreads();
    int* op = idx + (size_t)(b * N + gq) * KTOT;
    if (lg == 0) op[0] = gq;
    unsigned e = (unsigned)gq;
    if (lg < s_cnt) e = sbuf[grp][lg];
    else if (lg - s_cnt < t_cnt) e = tbuf[grp][lg - s_cnt];
    op[1 + lg] = (int)e;
}

// ---------------- fused edge MLP via MFMA ----------------
// Per block: 16 points. Loop k=0..16: gather f[67x16] -> GEMM1 (256x96 * 96x16)
// -> lrelu -> h1 LDS -> GEMM2 (128x256 * 256x16) -> running max.
__global__ __launch_bounds__(256) void ef_mlp_mfma(
        const float* __restrict__ lf, const float* __restrict__ pts,
        const int* __restrict__ idx,
        const unsigned short* __restrict__ W1p, const float* __restrict__ b_ef1,
        const unsigned short* __restrict__ W2p, const float* __restrict__ b_ef2,
        float* __restrict__ fmax_out) {
    const int t = threadIdx.x;
    const int w = t >> 6;       // wave 0..3
    const int l = t & 63;
    const int n0 = blockIdx.x * 16;
    const int b = blockIdx.y;

    __shared__ unsigned short f_lds[16][104];   // [p][c], K-major, pad->bank spread
    __shared__ unsigned short h1_lds[16][264];  // [p][m], pad
    __shared__ int idx_l[16][17];

    for (int e = t; e < 16 * 17; e += 256) {
        int p = e / 17, k = e - p * 17;
        idx_l[p][k] = idx[(size_t)(b * N + n0 + p) * KTOT + k];
    }
    for (int e = t; e < 16 * 37; e += 256) {    // zero pad c=67..103
        int p = e / 37, c = 67 + (e - p * 37);
        f_lds[p][c] = 0;
    }

    // per-lane biases
    float b1v[16];
#pragma unroll
    for (int mt = 0; mt < 4; ++mt)
#pragma unroll
        for (int r = 0; r < 4; ++r)
            b1v[mt * 4 + r] = b_ef1[(w * 4 + mt) * 16 + ((l >> 4) << 2) + r];
    float b2v[8];
#pragma unroll
    for (int i = 0; i < 2; ++i)
#pragma unroll
        for (int r = 0; r < 4; ++r)
            b2v[i * 4 + r] = b_ef2[(w * 2 + i) * 16 + ((l >> 4) << 2) + r];

    // A fragments (weights) — stay in registers for all 17 k-slots
    bf16x8 A1[12];
#pragma unroll
    for (int mt = 0; mt < 4; ++mt)
#pragma unroll
        for (int ks = 0; ks < 3; ++ks)
            A1[mt * 3 + ks] = *(const bf16x8*)(W1p + (size_t)(((w * 4 + mt) * 3 + ks) * 64 + l) * 8);
    bf16x8 A2[16];
#pragma unroll
    for (int i = 0; i < 2; ++i)
#pragma unroll
        for (int ks = 0; ks < 8; ++ks)
            A2[i * 8 + ks] = *(const bf16x8*)(W2p + (size_t)(((w * 2 + i) * 8 + ks) * 64 + l) * 8);

    const int p_my = t >> 4;
    const int cb = (t & 15) * 4;
    const float* lfb = lf + (size_t)b * CL * N;
    const float* ptsb = pts + (size_t)b * 3 * N;
    float selfp = 0.f;
    if (t < 48) selfp = ptsb[(size_t)(t >> 4) * N + n0 + (t & 15)];

    __syncthreads();  // idx_l + zero-pad visible

    float r0, r1, r2, r3, rp = 0.f;
    auto prefetch = [&](int k) {
        int j = idx_l[p_my][k];
        const float* col = lfb + j;
        r0 = col[(size_t)(cb + 0) * N];
        r1 = col[(size_t)(cb + 1) * N];
        r2 = col[(size_t)(cb + 2) * N];
        r3 = col[(size_t)(cb + 3) * N];
        if (t < 48) rp = ptsb[(size_t)(t >> 4) * N + idx_l[t & 15][k]];
    };
    auto commit = [&](int k) {
        union { unsigned short u[4]; uint2 d; } pk;
        pk.u[0] = f2bf(r0); pk.u[1] = f2bf(r1); pk.u[2] = f2bf(r2); pk.u[3] = f2bf(r3);
        *(uint2*)&f_lds[p_my][cb] = pk.d;
        if (t < 48) {
            float v = (k == 0) ? selfp : selfp - rp;
            f_lds[t & 15][64 + (t >> 4)] = f2bf(v);
        }
    };

    prefetch(0);
    f32x4 rmax0, rmax1;
#pragma unroll
    for (int r = 0; r < 4; ++r) { rmax0[r] = -1e30f; rmax1[r] = -1e30f; }

    for (int k = 0; k < KTOT; ++k) {
        commit(k);
        __syncthreads();                 // barrier A: f_lds(k) ready; GEMM2(k-1) done
        if (k < KTOT - 1) prefetch(k + 1);
        // GEMM1: B frags from f_lds
        bf16x8 Bf0 = *(const bf16x8*)&f_lds[l & 15][(l >> 4) * 8];
        bf16x8 Bf1 = *(const bf16x8*)&f_lds[l & 15][32 + (l >> 4) * 8];
        bf16x8 Bf2 = *(const bf16x8*)&f_lds[l & 15][64 + (l >> 4) * 8];
#pragma unroll
        for (int mt = 0; mt < 4; ++mt) {
            f32x4 acc = {0.f, 0.f, 0.f, 0.f};
            acc = __builtin_amdgcn_mfma_f32_16x16x32_bf16(A1[mt * 3 + 0], Bf0, acc, 0, 0, 0);
            acc = __builtin_amdgcn_mfma_f32_16x16x32_bf16(A1[mt * 3 + 1], Bf1, acc, 0, 0, 0);
            acc = __builtin_amdgcn_mfma_f32_16x16x32_bf16(A1[mt * 3 + 2], Bf2, acc, 0, 0, 0);
            union { unsigned short u[4]; uint2 d; } pk;
#pragma unroll
            for (int r = 0; r < 4; ++r)
                pk.u[r] = f2bf(lrelu(acc[r] + b1v[mt * 4 + r]));
            *(uint2*)&h1_lds[l & 15][(w * 4 + mt) * 16 + ((l >> 4) << 2)] = pk.d;
        }
        __syncthreads();                 // barrier B: h1(k) ready; GEMM1 reads done
        // GEMM2
        f32x4 a0 = {0.f, 0.f, 0.f, 0.f}, a1 = {0.f, 0.f, 0.f, 0.f};
#pragma unroll
        for (int ks = 0; ks < 8; ++ks) {
            bf16x8 B2 = *(const bf16x8*)&h1_lds[l & 15][ks * 32 + (l >> 4) * 8];
            a0 = __builtin_amdgcn_mfma_f32_16x16x32_bf16(A2[0 * 8 + ks], B2, a0, 0, 0, 0);
            a1 = __builtin_amdgcn_mfma_f32_16x16x32_bf16(A2[1 * 8 + ks], B2, a1, 0, 0, 0);
        }
#pragma unroll
        for (int r = 0; r < 4; ++r) {
            rmax0[r] = fmaxf(rmax0[r], a0[r]);
            rmax1[r] = fmaxf(rmax1[r], a1[r]);
        }
    }
    // store: o = (w*2+i)*16 + (l>>4)*4 + r, n = n0 + (l&15)
    const size_t nbase = ((size_t)(b * N + n0 + (l & 15))) * H2;
#pragma unroll
    for (int i = 0; i < 2; ++i) {
        f32x4 o;
        f32x4 rm = i ? rmax1 : rmax0;
#pragma unroll
        for (int r = 0; r < 4; ++r) o[r] = rm[r] + b2v[i * 4 + r];
        *(f32x4*)&fmax_out[nbase + (w * 2 + i) * 16 + ((l >> 4) << 2)] = o;
    }
}

// ---------------- fused final MLP: feat(195) -> 1024 -> lrelu -> 256 -> lrelu -> 1 ----------------
__global__ __launch_bounds__(256) void mlp_kernel(
        const float* __restrict__ lf, const float* __restrict__ pts,
        const float* __restrict__ fmax_in, const float* __restrict__ gvec,
        const float* __restrict__ W1t, const float* __restrict__ W2t,
        const float* __restrict__ W3, const float* __restrict__ b2v,
        const float* __restrict__ b3v, float* __restrict__ out) {
    const int t = threadIdx.x;
    const int n0 = blockIdx.x * 16;
    const int b = blockIdx.y;
    __shared__ float feat[KMLP * 17];
    __shared__ float y1c[256 * 17];
    __shared__ float y2s[O2 * 17];
    __shared__ float red[256];
    {
        int e = t;
#pragma unroll
        for (int it = 0; it < 4; ++it, e += 256) {
            int c = e >> 4, p = e & 15;
            feat[c * 17 + p] = lf[(size_t)(b * CL + c) * N + n0 + p];
        }
        e = t;
#pragma unroll
        for (int it = 0; it < 8; ++it, e += 256) {
            int cc = e & 127, pp = e >> 7;
            feat[(CL + cc) * 17 + pp] = fmax_in[(size_t)(b * N + n0 + pp) * H2 + cc];
        }
        if (t < 48) {
            int d = t >> 4, p = t & 15;
            feat[(CL + H2 + d) * 17 + p] = pts[(size_t)(b * 3 + d) * N + n0 + p];
        }
    }
    __syncthreads();
    float a2[16];
#pragma unroll
    for (int p = 0; p < 16; ++p) a2[p] = 0.f;
    for (int chunk = 0; chunk < 4; ++chunk) {
        const int o = chunk * 256 + t;
        float acc[16];
#pragma unroll
        for (int p = 0; p < 16; ++p) acc[p] = 0.f;
        for (int c = 0; c < KMLP; ++c) {
            float w = W1t[(size_t)c * O1 + o];
#pragma unroll
            for (int p = 0; p < 16; ++p) acc[p] = fmaf(w, feat[c * 17 + p], acc[p]);
        }
        float gb = gvec[b * O1 + o];
        if (chunk) __syncthreads();
#pragma unroll
        for (int p = 0; p < 16; ++p) y1c[t * 17 + p] = lrelu(acc[p] + gb);
        __syncthreads();
        for (int c = 0; c < 256; ++c) {
            float w = W2t[(size_t)(chunk * 256 + c) * O2 + t];
#pragma unroll
            for (int p = 0; p < 16; ++p) a2[p] = fmaf(w, y1c[c * 17 + p], a2[p]);
        }
    }
    float bb = b2v[t];
#pragma unroll
    for (int p = 0; p < 16; ++p) y2s[t * 17 + p] = lrelu(a2[p] + bb);
    __syncthreads();
    {
        const int p = t & 15, seg = t >> 4;
        float part = 0.f;
#pragma unroll
        for (int oo = 0; oo < 16; ++oo)
            part = fmaf(W3[seg * 16 + oo], y2s[(seg * 16 + oo) * 17 + p], part);
        red[t] = part;
    }
    __syncthreads();
    if (t < 16) {
        float s = b3v[0];
#pragma unroll
        for (int seg = 0; seg < 16; ++seg) s += red[seg * 16 + t];
        out[(size_t)b * N + n0 + t] = s;
    }
}

extern "C" void kernel_launch(void* const* d_in, const int* in_sizes, int n_in,
                              void* d_out, int out_size, void* d_ws, size_t ws_size,
                              hipStream_t stream) {
    const float* g     = (const float*)d_in[0];
    const float* pts   = (const float*)d_in[1];
    const float* lf    = (const float*)d_in[2];
    const float* W_ef1 = (const float*)d_in[3];
    const float* b_ef1 = (const float*)d_in[4];
    const float* W_ef2 = (const float*)d_in[5];
    const float* b_ef2 = (const float*)d_in[6];
    const float* W1    = (const float*)d_in[7];
    const float* b1    = (const float*)d_in[8];
    const float* W2    = (const float*)d_in[9];
    const float* b2    = (const float*)d_in[10];
    const float* W3    = (const float*)d_in[11];
    const float* b3    = (const float*)d_in[12];
    float* out = (float*)d_out;

    char* ws = (char*)d_ws;
    int*      idx   = (int*)ws;      ws += (size_t)B * N * KTOT * 4;
    unsigned* topd  = (unsigned*)ws;
    float*    fmax_ws = (float*)topd;   // alias: topd dead before ef_mlp writes fmax
    ws += (size_t)B * NCHUNK * 16 * N * 4;
    unsigned* Tbuf  = (unsigned*)ws; ws += (size_t)B * N * 4;
    float*    gvec  = (float*)ws;    ws += (size_t)B * O1 * 4;
    float*    W1t   = (float*)ws;    ws += (size_t)KMLP * O1 * 4;
    float*    W2t   = (float*)ws;    ws += (size_t)O1 * O2 * 4;
    unsigned short* W1p = (unsigned short*)ws; ws += (size_t)16 * 3 * 512 * 2;
    unsigned short* W2p = (unsigned short*)ws; ws += (size_t)8 * 8 * 512 * 2;

    transpose_w<<<dim3((KMLP * O1 + 255) / 256), 256, 0, stream>>>(W1, W1t, O1, KMLP, 1219, 1024);
    transpose_w<<<dim3((O1 * O2 + 255) / 256), 256, 0, stream>>>(W2, W2t, O2, O1, O1, 0);
    prepack_w1<<<dim3(96), 256, 0, stream>>>(W_ef1, W1p);
    prepack_w2<<<dim3(128), 256, 0, stream>>>(W_ef2, W2p);
    gvec_kernel<<<dim3(O1 / 256, B), 256, 0, stream>>>(W1, b1, g, gvec);
    knn_pass1<<<dim3(N / 256, NCHUNK, B), 256, 0, stream>>>(pts, topd);
    knn_thresh<<<dim3(N / 256, B), 256, 0, stream>>>(topd, Tbuf);
    knn_recover<<<dim3(N / 16, B), 256, 0, stream>>>(pts, Tbuf, idx);
    ef_mlp_mfma<<<dim3(N / 16, B), 256, 0, stream>>>(lf, pts, idx, W1p, b_ef1, W2p, b_ef2, fmax_ws);
    mlp_kernel<<<dim3(N / 16, B), 256, 0, stream>>>(lf, pts, fmax_ws, gvec, W1t, W2t, W3, b2, b3, out);
}

// Round 5
// 413.048 us; speedup vs baseline: 5.1388x; 1.8107x over previous
//
#include <hip/hip_runtime.h>
#include <hip/hip_bf16.h>
#include <cstdint>

#define B 2
#define N 8192
#define KTOT 17        // self + 16 neighbors
#define CL 64
#define CEF 67         // CL + 3
#define H1 256
#define H2 128
#define CG 1024
#define O1 1024
#define O2 256
#define NCHUNK 16
#define CHUNK (N / NCHUNK)   // 512

typedef unsigned long long u64;
typedef __bf16 bf16x8 __attribute__((ext_vector_type(8)));
typedef float f32x4 __attribute__((ext_vector_type(4)));

__device__ __forceinline__ float lrelu(float v) { return fmaxf(v, 0.01f * v); }

__device__ __forceinline__ unsigned short f2bf(float f) {  // RNE
    union { float f; unsigned u; } v; v.f = f;
    unsigned r = v.u + 0x7FFFu + ((v.u >> 16) & 1u);
    return (unsigned short)(r >> 16);
}

// ---------------- prepack ef weights into MFMA fragment order (bf16) ----------------
__global__ void prepack_w1(const float* __restrict__ W, unsigned short* __restrict__ out) {
    int id = blockIdx.x * 256 + threadIdx.x;          // 16*3*512 = 24576
    if (id >= 16 * 3 * 512) return;
    int j = id & 7, l = (id >> 3) & 63, rest = id >> 9;
    int ks = rest % 3, mt = rest / 3;
    int m = mt * 16 + (l & 15);
    int k = ks * 32 + ((l >> 4) << 3) + j;
    float v = (k < CEF) ? W[m * CEF + k] : 0.f;
    out[id] = f2bf(v);
}
__global__ void prepack_w2(const float* __restrict__ W, unsigned short* __restrict__ out) {
    int id = blockIdx.x * 256 + threadIdx.x;          // 8*8*512 = 32768
    if (id >= 8 * 8 * 512) return;
    int j = id & 7, l = (id >> 3) & 63, rest = id >> 9;
    int ks = rest & 7, mt = rest >> 3;
    int m = mt * 16 + (l & 15);
    int k = ks * 32 + ((l >> 4) << 3) + j;
    out[id] = f2bf(W[m * H1 + k]);
}

// ---------------- prepack mlp weights: W1eff (1024 x 195->224), W2 (256 x 1024) ----------------
// frag layout: [ch][w][mt][ks][lane][8]; m/k per the verified 16x16x32 A-mapping.
__global__ void prepack_mw1(const float* __restrict__ W1, unsigned short* __restrict__ out) {
    int id = blockIdx.x * 256 + threadIdx.x;          // 4*4*4*7*512 = 229376
    if (id >= 229376) return;
    int j = id & 7, l = (id >> 3) & 63, rest = id >> 9;   // rest < 448
    int ks = rest % 7; int rest2 = rest / 7;              // rest2 < 64
    int mt = rest2 & 3, w = (rest2 >> 2) & 3, ch = rest2 >> 4;
    int m = ch * 256 + w * 64 + mt * 16 + (l & 15);
    int k = ks * 32 + ((l >> 4) << 3) + j;
    out[id] = (k < 195) ? f2bf(W1[(size_t)m * 1219 + 1024 + k]) : (unsigned short)0;
}
__global__ void prepack_mw2(const float* __restrict__ W2, unsigned short* __restrict__ out) {
    int id = blockIdx.x * 256 + threadIdx.x;          // 4*4*4*8*512 = 262144
    if (id >= 262144) return;
    int j = id & 7, l = (id >> 3) & 63, rest = id >> 9;   // rest < 512
    int ks = rest & 7; int rest2 = rest >> 3;
    int mt = rest2 & 3, w = (rest2 >> 2) & 3, ch = rest2 >> 4;
    int m = w * 64 + mt * 16 + (l & 15);
    int k = ch * 256 + ks * 32 + ((l >> 4) << 3) + j;
    out[id] = f2bf(W2[(size_t)m * 1024 + k]);
}

// ---------------- gvec[b][o] = b1[o] + W1[o, 0:1024] . global_feat[b] ----------------
__global__ void gvec_kernel(const float* __restrict__ W1, const float* __restrict__ b1,
                            const float* __restrict__ g, float* __restrict__ gvec) {
    int o = blockIdx.x * 256 + threadIdx.x;
    int b = blockIdx.y;
    float s = b1[o];
    const float* row = W1 + (size_t)o * 1219;
    const float* gb = g + b * CG;
    for (int c = 0; c < CG; ++c) s = fmaf(row[c], gb[c], s);
    gvec[b * O1 + o] = s;
}

// ---------------- KNN pass1 ----------------
__global__ __launch_bounds__(256) void knn_pass1(const float* __restrict__ pts,
                                                 unsigned* __restrict__ topd) {
    const int t = threadIdx.x;
    const int i = blockIdx.x * 256 + t;
    const int chunk = blockIdx.y;
    const int b = blockIdx.z;
    const float* px = pts + (size_t)b * 3 * N;
    const float* py = px + N;
    const float* pz = py + N;
    const float qx = px[i], qy = py[i], qz = pz[i];
    const float qq = __fadd_rn(__fadd_rn(__fmul_rn(qx, qx), __fmul_rn(qy, qy)),
                               __fmul_rn(qz, qz));
    const float negqq = -qq;
    unsigned qd[16];
#pragma unroll
    for (int r = 0; r < 16; ++r) qd[r] = 0xFFFFFFFFu;
    __shared__ float4 cand[256];
    const int base = chunk * CHUNK;
    for (int tile = 0; tile < CHUNK / 256; ++tile) {
        const int j0 = base + tile * 256;
        __syncthreads();
        {
            float cx = px[j0 + t], cy = py[j0 + t], cz = pz[j0 + t];
            float cxx = __fadd_rn(__fadd_rn(__fmul_rn(cx, cx), __fmul_rn(cy, cy)),
                                  __fmul_rn(cz, cz));
            cand[t] = make_float4(cx, cy, cz, cxx);
        }
        __syncthreads();
#pragma unroll 4
        for (int s = 0; s < 256; ++s) {
            float4 c = cand[s];
            float dot = __fadd_rn(__fadd_rn(__fmul_rn(qx, c.x), __fmul_rn(qy, c.y)),
                                  __fmul_rn(qz, c.z));
            float inner = __fmul_rn(-2.f, dot);
            float pair = __fsub_rn(__fsub_rn(negqq, inner), c.w);
            float key = fmaxf(-pair, 0.f);
            unsigned pk = __float_as_uint(key);
            if (j0 + s == i) pk = 0xFFFFFFFFu;  // exclude self
#pragma unroll
            for (int r = 15; r >= 1; --r) {
                unsigned hi = pk > qd[r - 1] ? pk : qd[r - 1];
                qd[r] = hi < qd[r] ? hi : qd[r];
            }
            qd[0] = pk < qd[0] ? pk : qd[0];
        }
    }
#pragma unroll
    for (int s = 0; s < 16; ++s)
        topd[(size_t)((b * NCHUNK + chunk) * 16 + s) * N + i] = qd[s];
}

// ---------------- KNN thresh ----------------
__global__ __launch_bounds__(256) void knn_thresh(const unsigned* __restrict__ topd,
                                                  unsigned* __restrict__ Tbuf) {
    const int t = threadIdx.x;
    const int i = blockIdx.x * 256 + t;
    const int b = blockIdx.y;
    unsigned qd[16];
#pragma unroll
    for (int s = 0; s < 16; ++s)
        qd[s] = topd[(size_t)((b * NCHUNK + 0) * 16 + s) * N + i];
    for (int c = 1; c < NCHUNK; ++c) {
        for (int s = 0; s < 16; ++s) {
            unsigned pk = topd[(size_t)((b * NCHUNK + c) * 16 + s) * N + i];
            if (pk >= qd[15]) break;
#pragma unroll
            for (int r = 15; r >= 1; --r) {
                unsigned hi = pk > qd[r - 1] ? pk : qd[r - 1];
                qd[r] = hi < qd[r] ? hi : qd[r];
            }
            qd[0] = pk < qd[0] ? pk : qd[0];
        }
    }
    Tbuf[b * N + i] = qd[15];
}

// ---------------- KNN recover ----------------
__global__ __launch_bounds__(256) void knn_recover(const float* __restrict__ pts,
                                                   const unsigned* __restrict__ Tbuf,
                                                   int* __restrict__ idx) {
    const int t = threadIdx.x;
    const int lg = t & 15;
    const int grp = t >> 4;
    const int b = blockIdx.y;
    const int gq = blockIdx.x * 16 + grp;
    const float* px = pts + (size_t)b * 3 * N;
    const float* py = px + N;
    const float* pz = py + N;
    __shared__ float4 cand[256];
    __shared__ unsigned sbuf[16][16];
    __shared__ unsigned tbuf[16][32];
    __shared__ int scnt[16], tcnt[16];
    if (t < 16) { scnt[t] = 0; tcnt[t] = 0; }
    const float qx = px[gq], qy = py[gq], qz = pz[gq];
    const float qq = __fadd_rn(__fadd_rn(__fmul_rn(qx, qx), __fmul_rn(qy, qy)),
                               __fmul_rn(qz, qz));
    const float negqq = -qq;
    const unsigned T = Tbuf[b * N + gq];
    for (int tile = 0; tile < N / 256; ++tile) {
        const int j0 = tile * 256;
        __syncthreads();
        {
            float cx = px[j0 + t], cy = py[j0 + t], cz = pz[j0 + t];
            float cxx = __fadd_rn(__fadd_rn(__fmul_rn(cx, cx), __fmul_rn(cy, cy)),
                                  __fmul_rn(cz, cz));
            cand[t] = make_float4(cx, cy, cz, cxx);
        }
        __syncthreads();
        for (int it = 0; it < 16; ++it) {
            int s = it * 16 + lg;
            float4 c = cand[s];
            float dot = __fadd_rn(__fadd_rn(__fmul_rn(qx, c.x), __fmul_rn(qy, c.y)),
                                  __fmul_rn(qz, c.z));
            float inner = __fmul_rn(-2.f, dot);
            float pair = __fsub_rn(__fsub_rn(negqq, inner), c.w);
            float key = fmaxf(-pair, 0.f);
            unsigned pk = __float_as_uint(key);
            int j = j0 + s;
            bool hit = (j != gq) && (pk <= T);
            if (__any(hit)) {
                if (hit) {
                    if (pk < T) {
                        int p = atomicAdd(&scnt[grp], 1);
                        if (p < 16) sbuf[grp][p] = (unsigned)j;
                    } else {
                        int p = atomicAdd(&tcnt[grp], 1);
                        if (p < 32) tbuf[grp][p] = (unsigned)j;
                    }
                }
            }
        }
    }
    __syncthreads();
    int s_cnt = scnt[grp];
    int t_cnt = tcnt[grp]; if (t_cnt > 32) t_cnt = 32;
    int need = 16 - s_cnt;
    if (t_cnt > need && lg == 0) {
        for (int a = 1; a < t_cnt; ++a) {
            unsigned v = tbuf[grp][a]; int bq = a;
            while (bq > 0 && tbuf[grp][bq - 1] > v) { tbuf[grp][bq] = tbuf[grp][bq - 1]; --bq; }
            tbuf[grp][bq] = v;
        }
    }
    __syncthreads();
    int* op = idx + (size_t)(b * N + gq) * KTOT;
    if (lg == 0) op[0] = gq;
    unsigned e = (unsigned)gq;
    if (lg < s_cnt) e = sbuf[grp][lg];
    else if (lg - s_cnt < t_cnt) e = tbuf[grp][lg - s_cnt];
    op[1 + lg] = (int)e;
}

// ---------------- fused edge MLP via MFMA ----------------
__global__ __launch_bounds__(256) void ef_mlp_mfma(
        const float* __restrict__ lf, const float* __restrict__ pts,
        const int* __restrict__ idx,
        const unsigned short* __restrict__ W1p, const float* __restrict__ b_ef1,
        const unsigned short* __restrict__ W2p, const float* __restrict__ b_ef2,
        float* __restrict__ fmax_out) {
    const int t = threadIdx.x;
    const int w = t >> 6;       // wave 0..3
    const int l = t & 63;
    const int n0 = blockIdx.x * 16;
    const int b = blockIdx.y;

    __shared__ unsigned short f_lds[16][104];   // [p][c], K-major
    __shared__ unsigned short h1_lds[16][264];  // [p][m]
    __shared__ int idx_l[16][17];

    for (int e = t; e < 16 * 17; e += 256) {
        int p = e / 17, k = e - p * 17;
        idx_l[p][k] = idx[(size_t)(b * N + n0 + p) * KTOT + k];
    }
    for (int e = t; e < 16 * 37; e += 256) {    // zero pad c=67..103
        int p = e / 37, c = 67 + (e - p * 37);
        f_lds[p][c] = 0;
    }

    float b1v[16];
#pragma unroll
    for (int mt = 0; mt < 4; ++mt)
#pragma unroll
        for (int r = 0; r < 4; ++r)
            b1v[mt * 4 + r] = b_ef1[(w * 4 + mt) * 16 + ((l >> 4) << 2) + r];
    float b2v[8];
#pragma unroll
    for (int i = 0; i < 2; ++i)
#pragma unroll
        for (int r = 0; r < 4; ++r)
            b2v[i * 4 + r] = b_ef2[(w * 2 + i) * 16 + ((l >> 4) << 2) + r];

    bf16x8 A1[12];
#pragma unroll
    for (int mt = 0; mt < 4; ++mt)
#pragma unroll
        for (int ks = 0; ks < 3; ++ks)
            A1[mt * 3 + ks] = *(const bf16x8*)(W1p + (size_t)(((w * 4 + mt) * 3 + ks) * 64 + l) * 8);
    bf16x8 A2[16];
#pragma unroll
    for (int i = 0; i < 2; ++i)
#pragma unroll
        for (int ks = 0; ks < 8; ++ks)
            A2[i * 8 + ks] = *(const bf16x8*)(W2p + (size_t)(((w * 2 + i) * 8 + ks) * 64 + l) * 8);

    const int p_my = t >> 4;
    const int cb = (t & 15) * 4;
    const float* lfb = lf + (size_t)b * CL * N;
    const float* ptsb = pts + (size_t)b * 3 * N;
    float selfp = 0.f;
    if (t < 48) selfp = ptsb[(size_t)(t >> 4) * N + n0 + (t & 15)];

    __syncthreads();

    float r0, r1, r2, r3, rp = 0.f;
    auto prefetch = [&](int k) {
        int j = idx_l[p_my][k];
        const float* col = lfb + j;
        r0 = col[(size_t)(cb + 0) * N];
        r1 = col[(size_t)(cb + 1) * N];
        r2 = col[(size_t)(cb + 2) * N];
        r3 = col[(size_t)(cb + 3) * N];
        if (t < 48) rp = ptsb[(size_t)(t >> 4) * N + idx_l[t & 15][k]];
    };
    auto commit = [&](int k) {
        union { unsigned short u[4]; uint2 d; } pk;
        pk.u[0] = f2bf(r0); pk.u[1] = f2bf(r1); pk.u[2] = f2bf(r2); pk.u[3] = f2bf(r3);
        *(uint2*)&f_lds[p_my][cb] = pk.d;
        if (t < 48) {
            float v = (k == 0) ? selfp : selfp - rp;
            f_lds[t & 15][64 + (t >> 4)] = f2bf(v);
        }
    };

    prefetch(0);
    f32x4 rmax0, rmax1;
#pragma unroll
    for (int r = 0; r < 4; ++r) { rmax0[r] = -1e30f; rmax1[r] = -1e30f; }

    for (int k = 0; k < KTOT; ++k) {
        commit(k);
        __syncthreads();
        if (k < KTOT - 1) prefetch(k + 1);
        bf16x8 Bf0 = *(const bf16x8*)&f_lds[l & 15][(l >> 4) * 8];
        bf16x8 Bf1 = *(const bf16x8*)&f_lds[l & 15][32 + (l >> 4) * 8];
        bf16x8 Bf2 = *(const bf16x8*)&f_lds[l & 15][64 + (l >> 4) * 8];
#pragma unroll
        for (int mt = 0; mt < 4; ++mt) {
            f32x4 acc = {0.f, 0.f, 0.f, 0.f};
            acc = __builtin_amdgcn_mfma_f32_16x16x32_bf16(A1[mt * 3 + 0], Bf0, acc, 0, 0, 0);
            acc = __builtin_amdgcn_mfma_f32_16x16x32_bf16(A1[mt * 3 + 1], Bf1, acc, 0, 0, 0);
            acc = __builtin_amdgcn_mfma_f32_16x16x32_bf16(A1[mt * 3 + 2], Bf2, acc, 0, 0, 0);
            union { unsigned short u[4]; uint2 d; } pk;
#pragma unroll
            for (int r = 0; r < 4; ++r)
                pk.u[r] = f2bf(lrelu(acc[r] + b1v[mt * 4 + r]));
            *(uint2*)&h1_lds[l & 15][(w * 4 + mt) * 16 + ((l >> 4) << 2)] = pk.d;
        }
        __syncthreads();
        f32x4 a0 = {0.f, 0.f, 0.f, 0.f}, a1 = {0.f, 0.f, 0.f, 0.f};
#pragma unroll
        for (int ks = 0; ks < 8; ++ks) {
            bf16x8 B2 = *(const bf16x8*)&h1_lds[l & 15][ks * 32 + (l >> 4) * 8];
            a0 = __builtin_amdgcn_mfma_f32_16x16x32_bf16(A2[0 * 8 + ks], B2, a0, 0, 0, 0);
            a1 = __builtin_amdgcn_mfma_f32_16x16x32_bf16(A2[1 * 8 + ks], B2, a1, 0, 0, 0);
        }
#pragma unroll
        for (int r = 0; r < 4; ++r) {
            rmax0[r] = fmaxf(rmax0[r], a0[r]);
            rmax1[r] = fmaxf(rmax1[r], a1[r]);
        }
    }
    const size_t nbase = ((size_t)(b * N + n0 + (l & 15))) * H2;
#pragma unroll
    for (int i = 0; i < 2; ++i) {
        f32x4 o;
        f32x4 rm = i ? rmax1 : rmax0;
#pragma unroll
        for (int r = 0; r < 4; ++r) o[r] = rm[r] + b2v[i * 4 + r];
        *(f32x4*)&fmax_out[nbase + (w * 2 + i) * 16 + ((l >> 4) << 2)] = o;
    }
}

// ---------------- fused final MLP via MFMA ----------------
// Per block: 32 points, 4 waves. 4 chunks of 256 W1-rows:
//   GEMM-A (256x224 * 224x32) -> gvec bias + lrelu -> y1c (bf16, LDS)
//   GEMM-B (256x256 * 256x32) accumulated across chunks
// Epilogue: b2 + lrelu + W3-dot folded in-register, shfl reduce.
// LDS rows padded to 512B with XOR swizzle byte^=((row&7)<<4) (T2).
__global__ __launch_bounds__(256) void mlp_mfma(
        const float* __restrict__ lf, const float* __restrict__ pts,
        const float* __restrict__ fmax_in, const float* __restrict__ gvec,
        const unsigned short* __restrict__ W1m, const unsigned short* __restrict__ W2m,
        const float* __restrict__ W3, const float* __restrict__ b2v,
        const float* __restrict__ b3v, float* __restrict__ out) {
    const int t = threadIdx.x;
    const int w = t >> 6;
    const int l = t & 63;
    const int n0 = blockIdx.x * 32;
    const int b = blockIdx.y;

    __shared__ unsigned short feat_s[32 * 256];   // [n][256], swizzled
    __shared__ unsigned short y1c_s[32 * 256];    // [n][256], swizzled
    __shared__ float red[4][32];

    auto sw = [](int n, int cbyte) -> unsigned {  // byte address with XOR swizzle
        return (unsigned)(n << 9) | ((unsigned)cbyte ^ (((unsigned)n & 7u) << 4));
    };
    char* featB = (char*)feat_s;
    char* y1cB = (char*)y1c_s;

    // ---- stage feat (bf16) ----
    const float* lfb = lf + (size_t)b * CL * N;
    for (int e = t; e < 32 * 64; e += 256) {       // local feats
        int n = e & 31, c = e >> 5;
        *(unsigned short*)(featB + sw(n, c * 2)) = f2bf(lfb[(size_t)c * N + n0 + n]);
    }
    for (int e = t; e < 32 * 128; e += 256) {      // fmax
        int c = e & 127, n = e >> 7;
        *(unsigned short*)(featB + sw(n, (64 + c) * 2)) =
            f2bf(fmax_in[((size_t)(b * N + n0 + n)) * H2 + c]);
    }
    for (int e = t; e < 32 * 3; e += 256) {        // xyz
        int n = e & 31, d = e >> 5;
        *(unsigned short*)(featB + sw(n, (192 + d) * 2)) =
            f2bf(pts[((size_t)(b * 3 + d)) * N + n0 + n]);
    }
    for (int e = t; e < 32 * 29; e += 256) {       // zero pad k=195..223
        int n = e / 29, c = 195 + e % 29;
        *(unsigned short*)(featB + sw(n, c * 2)) = 0;
    }
    __syncthreads();

    f32x4 accB[4][2];
#pragma unroll
    for (int mt = 0; mt < 4; ++mt)
#pragma unroll
        for (int nt = 0; nt < 2; ++nt)
            accB[mt][nt] = (f32x4){0.f, 0.f, 0.f, 0.f};

    for (int ch = 0; ch < 4; ++ch) {
        // ---- GEMM-A ----
        bf16x8 A1[4][7];
#pragma unroll
        for (int mt = 0; mt < 4; ++mt)
#pragma unroll
            for (int ks = 0; ks < 7; ++ks)
                A1[mt][ks] = *(const bf16x8*)(W1m +
                    (size_t)((((ch * 4 + w) * 4 + mt) * 7 + ks) * 64 + l) * 8);
        f32x4 accA[4][2];
#pragma unroll
        for (int mt = 0; mt < 4; ++mt)
#pragma unroll
            for (int nt = 0; nt < 2; ++nt)
                accA[mt][nt] = (f32x4){0.f, 0.f, 0.f, 0.f};
#pragma unroll
        for (int nt = 0; nt < 2; ++nt) {
            const int n = nt * 16 + (l & 15);
#pragma unroll
            for (int ks = 0; ks < 7; ++ks) {
                bf16x8 Bf = *(const bf16x8*)(featB + sw(n, ks * 64 + (l >> 4) * 16));
#pragma unroll
                for (int mt = 0; mt < 4; ++mt)
                    accA[mt][nt] = __builtin_amdgcn_mfma_f32_16x16x32_bf16(
                        A1[mt][ks], Bf, accA[mt][nt], 0, 0, 0);
            }
        }
        // issue GEMM-B weight loads early (independent of y1c)
        bf16x8 A2[4][8];
#pragma unroll
        for (int mt = 0; mt < 4; ++mt)
#pragma unroll
            for (int ks = 0; ks < 8; ++ks)
                A2[mt][ks] = *(const bf16x8*)(W2m +
                    (size_t)((((ch * 4 + w) * 4 + mt) * 8 + ks) * 64 + l) * 8);
        if (ch) __syncthreads();   // previous GEMM-B reads of y1c done
        // bias + lrelu -> y1c
#pragma unroll
        for (int mt = 0; mt < 4; ++mt) {
            const int m = w * 64 + mt * 16 + ((l >> 4) << 2);
            const f32x4 gv = *(const f32x4*)(gvec + b * O1 + ch * 256 + m);
#pragma unroll
            for (int nt = 0; nt < 2; ++nt) {
                const int n = nt * 16 + (l & 15);
                union { unsigned short u[4]; uint2 d; } pk;
#pragma unroll
                for (int r = 0; r < 4; ++r)
                    pk.u[r] = f2bf(lrelu(accA[mt][nt][r] + gv[r]));
                *(uint2*)(y1cB + sw(n, m * 2)) = pk.d;
            }
        }
        __syncthreads();
        // ---- GEMM-B (accumulate over chunks) ----
#pragma unroll
        for (int nt = 0; nt < 2; ++nt) {
            const int n = nt * 16 + (l & 15);
#pragma unroll
            for (int ks = 0; ks < 8; ++ks) {
                bf16x8 Bf = *(const bf16x8*)(y1cB + sw(n, ks * 64 + (l >> 4) * 16));
#pragma unroll
                for (int mt = 0; mt < 4; ++mt)
                    accB[mt][nt] = __builtin_amdgcn_mfma_f32_16x16x32_bf16(
                        A2[mt][ks], Bf, accB[mt][nt], 0, 0, 0);
            }
        }
    }

    // ---- epilogue: y2 = lrelu(accB + b2); partial = W3 . y2 ----
    float p0 = 0.f, p1 = 0.f;
#pragma unroll
    for (int mt = 0; mt < 4; ++mt) {
        const int m = w * 64 + mt * 16 + ((l >> 4) << 2);
        const f32x4 bb = *(const f32x4*)(b2v + m);
        const f32x4 w3 = *(const f32x4*)(W3 + m);
#pragma unroll
        for (int r = 0; r < 4; ++r) {
            p0 = fmaf(w3[r], lrelu(accB[mt][0][r] + bb[r]), p0);
            p1 = fmaf(w3[r], lrelu(accB[mt][1][r] + bb[r]), p1);
        }
    }
    p0 += __shfl_xor(p0, 16); p0 += __shfl_xor(p0, 32);
    p1 += __shfl_xor(p1, 16); p1 += __shfl_xor(p1, 32);
    if (l < 16) { red[w][l] = p0; red[w][16 + l] = p1; }
    __syncthreads();
    if (t < 32) {
        float s = b3v[0] + red[0][t] + red[1][t] + red[2][t] + red[3][t];
        out[(size_t)b * N + n0 + t] = s;
    }
}

extern "C" void kernel_launch(void* const* d_in, const int* in_sizes, int n_in,
                              void* d_out, int out_size, void* d_ws, size_t ws_size,
                              hipStream_t stream) {
    const float* g     = (const float*)d_in[0];
    const float* pts   = (const float*)d_in[1];
    const float* lf    = (const float*)d_in[2];
    const float* W_ef1 = (const float*)d_in[3];
    const float* b_ef1 = (const float*)d_in[4];
    const float* W_ef2 = (const float*)d_in[5];
    const float* b_ef2 = (const float*)d_in[6];
    const float* W1    = (const float*)d_in[7];
    const float* b1    = (const float*)d_in[8];
    const float* W2    = (const float*)d_in[9];
    const float* b2    = (const float*)d_in[10];
    const float* W3    = (const float*)d_in[11];
    const float* b3    = (const float*)d_in[12];
    float* out = (float*)d_out;

    char* ws = (char*)d_ws;
    int*      idx   = (int*)ws;      ws += (size_t)B * N * KTOT * 4;
    unsigned* topd  = (unsigned*)ws;
    float*    fmax_ws = (float*)topd;   // alias: topd dead before ef_mlp writes fmax
    ws += (size_t)B * NCHUNK * 16 * N * 4;
    unsigned* Tbuf  = (unsigned*)ws; ws += (size_t)B * N * 4;
    float*    gvec  = (float*)ws;    ws += (size_t)B * O1 * 4;
    unsigned short* W1p = (unsigned short*)ws; ws += (size_t)16 * 3 * 512 * 2;
    unsigned short* W2p = (unsigned short*)ws; ws += (size_t)8 * 8 * 512 * 2;
    unsigned short* W1m = (unsigned short*)ws; ws += (size_t)229376 * 2;
    unsigned short* W2m = (unsigned short*)ws; ws += (size_t)262144 * 2;

    prepack_w1<<<dim3(96), 256, 0, stream>>>(W_ef1, W1p);
    prepack_w2<<<dim3(128), 256, 0, stream>>>(W_ef2, W2p);
    prepack_mw1<<<dim3(896), 256, 0, stream>>>(W1, W1m);
    prepack_mw2<<<dim3(1024), 256, 0, stream>>>(W2, W2m);
    gvec_kernel<<<dim3(O1 / 256, B), 256, 0, stream>>>(W1, b1, g, gvec);
    knn_pass1<<<dim3(N / 256, NCHUNK, B), 256, 0, stream>>>(pts, topd);
    knn_thresh<<<dim3(N / 256, B), 256, 0, stream>>>(topd, Tbuf);
    knn_recover<<<dim3(N / 16, B), 256, 0, stream>>>(pts, Tbuf, idx);
    ef_mlp_mfma<<<dim3(N / 16, B), 256, 0, stream>>>(lf, pts, idx, W1p, b_ef1, W2p, b_ef2, fmax_ws);
    mlp_mfma<<<dim3(N / 32, B), 256, 0, stream>>>(lf, pts, fmax_ws, gvec, W1m, W2m, W3, b2, b3, out);
}

// Round 6
// 349.185 us; speedup vs baseline: 6.0786x; 1.1829x over previous
//
#include <hip/hip_runtime.h>
#include <hip/hip_bf16.h>
#include <cstdint>

#define B 2
#define N 8192
#define KTOT 17        // self + 16 neighbors
#define CL 64
#define CEF 67         // CL + 3
#define H1 256
#define H2 128
#define CG 1024
#define O1 1024
#define O2 256
#define NCHUNK 16
#define CHUNK (N / NCHUNK)   // 512

typedef unsigned long long u64;
typedef __bf16 bf16x8 __attribute__((ext_vector_type(8)));
typedef float f32x4 __attribute__((ext_vector_type(4)));

__device__ __forceinline__ float lrelu(float v) { return fmaxf(v, 0.01f * v); }

__device__ __forceinline__ unsigned short f2bf(float f) {  // RNE
    union { float f; unsigned u; } v; v.f = f;
    unsigned r = v.u + 0x7FFFu + ((v.u >> 16) & 1u);
    return (unsigned short)(r >> 16);
}

// squared-norm and distance key — MUST be used identically in pass1 & recover
// so threshold compares are bit-exact between the two kernels.
__device__ __forceinline__ float norm3(float x, float y, float z) {
    return __fmaf_rn(z, z, __fmaf_rn(y, y, __fmul_rn(x, x)));
}
__device__ __forceinline__ float dist_key(float qx, float qy, float qz, float qq,
                                          float cx, float cy, float cz, float cxx) {
    float dot = __fmaf_rn(qz, cz, __fmaf_rn(qy, cy, __fmul_rn(qx, cx)));
    float t = __fmaf_rn(-2.f, dot, qq);
    return fmaxf(__fadd_rn(t, cxx), 0.f);
}

// ---------------- prepack ef weights into MFMA fragment order (bf16) ----------------
__global__ void prepack_w1(const float* __restrict__ W, unsigned short* __restrict__ out) {
    int id = blockIdx.x * 256 + threadIdx.x;          // 16*3*512 = 24576
    if (id >= 16 * 3 * 512) return;
    int j = id & 7, l = (id >> 3) & 63, rest = id >> 9;
    int ks = rest % 3, mt = rest / 3;
    int m = mt * 16 + (l & 15);
    int k = ks * 32 + ((l >> 4) << 3) + j;
    float v = (k < CEF) ? W[m * CEF + k] : 0.f;
    out[id] = f2bf(v);
}
__global__ void prepack_w2(const float* __restrict__ W, unsigned short* __restrict__ out) {
    int id = blockIdx.x * 256 + threadIdx.x;          // 8*8*512 = 32768
    if (id >= 8 * 8 * 512) return;
    int j = id & 7, l = (id >> 3) & 63, rest = id >> 9;
    int ks = rest & 7, mt = rest >> 3;
    int m = mt * 16 + (l & 15);
    int k = ks * 32 + ((l >> 4) << 3) + j;
    out[id] = f2bf(W[m * H1 + k]);
}

// ---------------- prepack mlp weights ----------------
__global__ void prepack_mw1(const float* __restrict__ W1, unsigned short* __restrict__ out) {
    int id = blockIdx.x * 256 + threadIdx.x;          // 229376
    if (id >= 229376) return;
    int j = id & 7, l = (id >> 3) & 63, rest = id >> 9;
    int ks = rest % 7; int rest2 = rest / 7;
    int mt = rest2 & 3, w = (rest2 >> 2) & 3, ch = rest2 >> 4;
    int m = ch * 256 + w * 64 + mt * 16 + (l & 15);
    int k = ks * 32 + ((l >> 4) << 3) + j;
    out[id] = (k < 195) ? f2bf(W1[(size_t)m * 1219 + 1024 + k]) : (unsigned short)0;
}
__global__ void prepack_mw2(const float* __restrict__ W2, unsigned short* __restrict__ out) {
    int id = blockIdx.x * 256 + threadIdx.x;          // 262144
    if (id >= 262144) return;
    int j = id & 7, l = (id >> 3) & 63, rest = id >> 9;
    int ks = rest & 7; int rest2 = rest >> 3;
    int mt = rest2 & 3, w = (rest2 >> 2) & 3, ch = rest2 >> 4;
    int m = w * 64 + mt * 16 + (l & 15);
    int k = ch * 256 + ks * 32 + ((l >> 4) << 3) + j;
    out[id] = f2bf(W2[(size_t)m * 1024 + k]);
}

// ---------------- gvec[b][o] = b1[o] + W1[o, 0:1024] . global_feat[b] ----------------
__global__ void gvec_kernel(const float* __restrict__ W1, const float* __restrict__ b1,
                            const float* __restrict__ g, float* __restrict__ gvec) {
    int o = blockIdx.x * 256 + threadIdx.x;
    int b = blockIdx.y;
    float s = b1[o];
    const float* row = W1 + (size_t)o * 1219;
    const float* gb = g + b * CG;
    for (int c = 0; c < CG; ++c) s = fmaf(row[c], gb[c], s);
    gvec[b * O1 + o] = s;
}

// ---------------- KNN pass1: value-only top-16 via v_med3_f32 chain ----------------
__global__ __launch_bounds__(256) void knn_pass1(const float* __restrict__ pts,
                                                 float* __restrict__ topd) {
    const int t = threadIdx.x;
    const int i = blockIdx.x * 256 + t;
    const int chunk = blockIdx.y;
    const int b = blockIdx.z;
    const float* px = pts + (size_t)b * 3 * N;
    const float* py = px + N;
    const float* pz = py + N;
    const float qx = px[i], qy = py[i], qz = pz[i];
    const float qq = norm3(qx, qy, qz);
    float qd[16];
#pragma unroll
    for (int r = 0; r < 16; ++r) qd[r] = __builtin_inff();
    __shared__ float4 cand[256];
    const int base = chunk * CHUNK;
    for (int tile = 0; tile < CHUNK / 256; ++tile) {
        const int j0 = base + tile * 256;
        __syncthreads();
        {
            float cx = px[j0 + t], cy = py[j0 + t], cz = pz[j0 + t];
            cand[t] = make_float4(cx, cy, cz, norm3(cx, cy, cz));
        }
        __syncthreads();
#pragma unroll 4
        for (int s = 0; s < 256; ++s) {
            float4 c = cand[s];
            float key = dist_key(qx, qy, qz, qq, c.x, c.y, c.z, c.w);
            if (j0 + s == i) key = __builtin_inff();  // exclude self
#pragma unroll
            for (int r = 15; r >= 1; --r)
                qd[r] = __builtin_amdgcn_fmed3f(key, qd[r - 1], qd[r]);
            qd[0] = fminf(key, qd[0]);
        }
    }
#pragma unroll
    for (int s = 0; s < 16; ++s)
        topd[(size_t)((b * NCHUNK + chunk) * 16 + s) * N + i] = qd[s];
}

// ---------------- KNN thresh: merge chunk lists -> global 16th smallest distance T ----------------
__global__ __launch_bounds__(256) void knn_thresh(const float* __restrict__ topd,
                                                  float* __restrict__ Tbuf) {
    const int t = threadIdx.x;
    const int i = blockIdx.x * 256 + t;
    const int b = blockIdx.y;
    float qd[16];
#pragma unroll
    for (int s = 0; s < 16; ++s)
        qd[s] = topd[(size_t)((b * NCHUNK + 0) * 16 + s) * N + i];
    for (int c = 1; c < NCHUNK; ++c) {
        for (int s = 0; s < 16; ++s) {
            float pk = topd[(size_t)((b * NCHUNK + c) * 16 + s) * N + i];
            if (pk >= qd[15]) break;  // sorted: rest of chunk also fails
#pragma unroll
            for (int r = 15; r >= 1; --r)
                qd[r] = __builtin_amdgcn_fmed3f(pk, qd[r - 1], qd[r]);
            qd[0] = fminf(pk, qd[0]);
        }
    }
    Tbuf[b * N + i] = qd[15];
}

// ---------------- KNN recover: rescan, collect indices with d<T (+ d==T ties) ----------------
__global__ __launch_bounds__(256) void knn_recover(const float* __restrict__ pts,
                                                   const float* __restrict__ Tbuf,
                                                   int* __restrict__ idx) {
    const int t = threadIdx.x;
    const int lg = t & 15;
    const int grp = t >> 4;
    const int b = blockIdx.y;
    const int gq = blockIdx.x * 16 + grp;
    const float* px = pts + (size_t)b * 3 * N;
    const float* py = px + N;
    const float* pz = py + N;
    __shared__ float4 cand[256];
    __shared__ unsigned sbuf[16][16];
    __shared__ unsigned tbuf[16][32];
    __shared__ int scnt[16], tcnt[16];
    if (t < 16) { scnt[t] = 0; tcnt[t] = 0; }
    const float qx = px[gq], qy = py[gq], qz = pz[gq];
    const float qq = norm3(qx, qy, qz);
    const float T = Tbuf[b * N + gq];
    for (int tile = 0; tile < N / 256; ++tile) {
        const int j0 = tile * 256;
        __syncthreads();
        {
            float cx = px[j0 + t], cy = py[j0 + t], cz = pz[j0 + t];
            cand[t] = make_float4(cx, cy, cz, norm3(cx, cy, cz));
        }
        __syncthreads();
        for (int it = 0; it < 16; ++it) {
            int s = it * 16 + lg;
            float4 c = cand[s];
            float key = dist_key(qx, qy, qz, qq, c.x, c.y, c.z, c.w);
            int j = j0 + s;
            bool hit = (j != gq) && (key <= T);
            if (__any(hit)) {
                if (hit) {
                    if (key < T) {
                        int p = atomicAdd(&scnt[grp], 1);
                        if (p < 16) sbuf[grp][p] = (unsigned)j;
                    } else {
                        int p = atomicAdd(&tcnt[grp], 1);
                        if (p < 32) tbuf[grp][p] = (unsigned)j;
                    }
                }
            }
        }
    }
    __syncthreads();
    int s_cnt = scnt[grp];
    int t_cnt = tcnt[grp]; if (t_cnt > 32) t_cnt = 32;
    int need = 16 - s_cnt;
    if (t_cnt > need && lg == 0) {  // rare: sort ties ascending by index
        for (int a = 1; a < t_cnt; ++a) {
            unsigned v = tbuf[grp][a]; int bq = a;
            while (bq > 0 && tbuf[grp][bq - 1] > v) { tbuf[grp][bq] = tbuf[grp][bq - 1]; --bq; }
            tbuf[grp][bq] = v;
        }
    }
    __syncthreads();
    int* op = idx + (size_t)(b * N + gq) * KTOT;
    if (lg == 0) op[0] = gq;
    unsigned e = (unsigned)gq;
    if (lg < s_cnt) e = sbuf[grp][lg];
    else if (lg - s_cnt < t_cnt) e = tbuf[grp][lg - s_cnt];
    op[1 + lg] = (int)e;
}

// ---------------- fused edge MLP via MFMA ----------------
__global__ __launch_bounds__(256) void ef_mlp_mfma(
        const float* __restrict__ lf, const float* __restrict__ pts,
        const int* __restrict__ idx,
        const unsigned short* __restrict__ W1p, const float* __restrict__ b_ef1,
        const unsigned short* __restrict__ W2p, const float* __restrict__ b_ef2,
        float* __restrict__ fmax_out) {
    const int t = threadIdx.x;
    const int w = t >> 6;       // wave 0..3
    const int l = t & 63;
    const int n0 = blockIdx.x * 16;
    const int b = blockIdx.y;

    __shared__ unsigned short f_lds[16][104];   // [p][c], K-major
    __shared__ unsigned short h1_lds[16][264];  // [p][m]
    __shared__ int idx_l[16][17];

    for (int e = t; e < 16 * 17; e += 256) {
        int p = e / 17, k = e - p * 17;
        idx_l[p][k] = idx[(size_t)(b * N + n0 + p) * KTOT + k];
    }
    for (int e = t; e < 16 * 37; e += 256) {    // zero pad c=67..103
        int p = e / 37, c = 67 + (e - p * 37);
        f_lds[p][c] = 0;
    }

    float b1v[16];
#pragma unroll
    for (int mt = 0; mt < 4; ++mt)
#pragma unroll
        for (int r = 0; r < 4; ++r)
            b1v[mt * 4 + r] = b_ef1[(w * 4 + mt) * 16 + ((l >> 4) << 2) + r];
    float b2v[8];
#pragma unroll
    for (int i = 0; i < 2; ++i)
#pragma unroll
        for (int r = 0; r < 4; ++r)
            b2v[i * 4 + r] = b_ef2[(w * 2 + i) * 16 + ((l >> 4) << 2) + r];

    bf16x8 A1[12];
#pragma unroll
    for (int mt = 0; mt < 4; ++mt)
#pragma unroll
        for (int ks = 0; ks < 3; ++ks)
            A1[mt * 3 + ks] = *(const bf16x8*)(W1p + (size_t)(((w * 4 + mt) * 3 + ks) * 64 + l) * 8);
    bf16x8 A2[16];
#pragma unroll
    for (int i = 0; i < 2; ++i)
#pragma unroll
        for (int ks = 0; ks < 8; ++ks)
            A2[i * 8 + ks] = *(const bf16x8*)(W2p + (size_t)(((w * 2 + i) * 8 + ks) * 64 + l) * 8);

    const int p_my = t >> 4;
    const int cb = (t & 15) * 4;
    const float* lfb = lf + (size_t)b * CL * N;
    const float* ptsb = pts + (size_t)b * 3 * N;
    float selfp = 0.f;
    if (t < 48) selfp = ptsb[(size_t)(t >> 4) * N + n0 + (t & 15)];

    __syncthreads();

    float r0, r1, r2, r3, rp = 0.f;
    auto prefetch = [&](int k) {
        int j = idx_l[p_my][k];
        const float* col = lfb + j;
        r0 = col[(size_t)(cb + 0) * N];
        r1 = col[(size_t)(cb + 1) * N];
        r2 = col[(size_t)(cb + 2) * N];
        r3 = col[(size_t)(cb + 3) * N];
        if (t < 48) rp = ptsb[(size_t)(t >> 4) * N + idx_l[t & 15][k]];
    };
    auto commit = [&](int k) {
        union { unsigned short u[4]; uint2 d; } pk;
        pk.u[0] = f2bf(r0); pk.u[1] = f2bf(r1); pk.u[2] = f2bf(r2); pk.u[3] = f2bf(r3);
        *(uint2*)&f_lds[p_my][cb] = pk.d;
        if (t < 48) {
            float v = (k == 0) ? selfp : selfp - rp;
            f_lds[t & 15][64 + (t >> 4)] = f2bf(v);
        }
    };

    prefetch(0);
    f32x4 rmax0, rmax1;
#pragma unroll
    for (int r = 0; r < 4; ++r) { rmax0[r] = -1e30f; rmax1[r] = -1e30f; }

    for (int k = 0; k < KTOT; ++k) {
        commit(k);
        __syncthreads();
        if (k < KTOT - 1) prefetch(k + 1);
        bf16x8 Bf0 = *(const bf16x8*)&f_lds[l & 15][(l >> 4) * 8];
        bf16x8 Bf1 = *(const bf16x8*)&f_lds[l & 15][32 + (l >> 4) * 8];
        bf16x8 Bf2 = *(const bf16x8*)&f_lds[l & 15][64 + (l >> 4) * 8];
#pragma unroll
        for (int mt = 0; mt < 4; ++mt) {
            f32x4 acc = {0.f, 0.f, 0.f, 0.f};
            acc = __builtin_amdgcn_mfma_f32_16x16x32_bf16(A1[mt * 3 + 0], Bf0, acc, 0, 0, 0);
            acc = __builtin_amdgcn_mfma_f32_16x16x32_bf16(A1[mt * 3 + 1], Bf1, acc, 0, 0, 0);
            acc = __builtin_amdgcn_mfma_f32_16x16x32_bf16(A1[mt * 3 + 2], Bf2, acc, 0, 0, 0);
            union { unsigned short u[4]; uint2 d; } pk;
#pragma unroll
            for (int r = 0; r < 4; ++r)
                pk.u[r] = f2bf(lrelu(acc[r] + b1v[mt * 4 + r]));
            *(uint2*)&h1_lds[l & 15][(w * 4 + mt) * 16 + ((l >> 4) << 2)] = pk.d;
        }
        __syncthreads();
        f32x4 a0 = {0.f, 0.f, 0.f, 0.f}, a1 = {0.f, 0.f, 0.f, 0.f};
#pragma unroll
        for (int ks = 0; ks < 8; ++ks) {
            bf16x8 B2 = *(const bf16x8*)&h1_lds[l & 15][ks * 32 + (l >> 4) * 8];
            a0 = __builtin_amdgcn_mfma_f32_16x16x32_bf16(A2[0 * 8 + ks], B2, a0, 0, 0, 0);
            a1 = __builtin_amdgcn_mfma_f32_16x16x32_bf16(A2[1 * 8 + ks], B2, a1, 0, 0, 0);
        }
#pragma unroll
        for (int r = 0; r < 4; ++r) {
            rmax0[r] = fmaxf(rmax0[r], a0[r]);
            rmax1[r] = fmaxf(rmax1[r], a1[r]);
        }
    }
    const size_t nbase = ((size_t)(b * N + n0 + (l & 15))) * H2;
#pragma unroll
    for (int i = 0; i < 2; ++i) {
        f32x4 o;
        f32x4 rm = i ? rmax1 : rmax0;
#pragma unroll
        for (int r = 0; r < 4; ++r) o[r] = rm[r] + b2v[i * 4 + r];
        *(f32x4*)&fmax_out[nbase + (w * 2 + i) * 16 + ((l >> 4) << 2)] = o;
    }
}

// ---------------- fused final MLP via MFMA ----------------
__global__ __launch_bounds__(256) void mlp_mfma(
        const float* __restrict__ lf, const float* __restrict__ pts,
        const float* __restrict__ fmax_in, const float* __restrict__ gvec,
        const unsigned short* __restrict__ W1m, const unsigned short* __restrict__ W2m,
        const float* __restrict__ W3, const float* __restrict__ b2v,
        const float* __restrict__ b3v, float* __restrict__ out) {
    const int t = threadIdx.x;
    const int w = t >> 6;
    const int l = t & 63;
    const int n0 = blockIdx.x * 32;
    const int b = blockIdx.y;

    __shared__ unsigned short feat_s[32 * 256];   // [n][256], swizzled
    __shared__ unsigned short y1c_s[32 * 256];    // [n][256], swizzled
    __shared__ float red[4][32];

    auto sw = [](int n, int cbyte) -> unsigned {
        return (unsigned)(n << 9) | ((unsigned)cbyte ^ (((unsigned)n & 7u) << 4));
    };
    char* featB = (char*)feat_s;
    char* y1cB = (char*)y1c_s;

    const float* lfb = lf + (size_t)b * CL * N;
    for (int e = t; e < 32 * 64; e += 256) {
        int n = e & 31, c = e >> 5;
        *(unsigned short*)(featB + sw(n, c * 2)) = f2bf(lfb[(size_t)c * N + n0 + n]);
    }
    for (int e = t; e < 32 * 128; e += 256) {
        int c = e & 127, n = e >> 7;
        *(unsigned short*)(featB + sw(n, (64 + c) * 2)) =
            f2bf(fmax_in[((size_t)(b * N + n0 + n)) * H2 + c]);
    }
    for (int e = t; e < 32 * 3; e += 256) {
        int n = e & 31, d = e >> 5;
        *(unsigned short*)(featB + sw(n, (192 + d) * 2)) =
            f2bf(pts[((size_t)(b * 3 + d)) * N + n0 + n]);
    }
    for (int e = t; e < 32 * 29; e += 256) {
        int n = e / 29, c = 195 + e % 29;
        *(unsigned short*)(featB + sw(n, c * 2)) = 0;
    }
    __syncthreads();

    f32x4 accB[4][2];
#pragma unroll
    for (int mt = 0; mt < 4; ++mt)
#pragma unroll
        for (int nt = 0; nt < 2; ++nt)
            accB[mt][nt] = (f32x4){0.f, 0.f, 0.f, 0.f};

    for (int ch = 0; ch < 4; ++ch) {
        bf16x8 A1[4][7];
#pragma unroll
        for (int mt = 0; mt < 4; ++mt)
#pragma unroll
            for (int ks = 0; ks < 7; ++ks)
                A1[mt][ks] = *(const bf16x8*)(W1m +
                    (size_t)((((ch * 4 + w) * 4 + mt) * 7 + ks) * 64 + l) * 8);
        f32x4 accA[4][2];
#pragma unroll
        for (int mt = 0; mt < 4; ++mt)
#pragma unroll
            for (int nt = 0; nt < 2; ++nt)
                accA[mt][nt] = (f32x4){0.f, 0.f, 0.f, 0.f};
#pragma unroll
        for (int nt = 0; nt < 2; ++nt) {
            const int n = nt * 16 + (l & 15);
#pragma unroll
            for (int ks = 0; ks < 7; ++ks) {
                bf16x8 Bf = *(const bf16x8*)(featB + sw(n, ks * 64 + (l >> 4) * 16));
#pragma unroll
                for (int mt = 0; mt < 4; ++mt)
                    accA[mt][nt] = __builtin_amdgcn_mfma_f32_16x16x32_bf16(
                        A1[mt][ks], Bf, accA[mt][nt], 0, 0, 0);
            }
        }
        bf16x8 A2[4][8];
#pragma unroll
        for (int mt = 0; mt < 4; ++mt)
#pragma unroll
            for (int ks = 0; ks < 8; ++ks)
                A2[mt][ks] = *(const bf16x8*)(W2m +
                    (size_t)((((ch * 4 + w) * 4 + mt) * 8 + ks) * 64 + l) * 8);
        if (ch) __syncthreads();
#pragma unroll
        for (int mt = 0; mt < 4; ++mt) {
            const int m = w * 64 + mt * 16 + ((l >> 4) << 2);
            const f32x4 gv = *(const f32x4*)(gvec + b * O1 + ch * 256 + m);
#pragma unroll
            for (int nt = 0; nt < 2; ++nt) {
                const int n = nt * 16 + (l & 15);
                union { unsigned short u[4]; uint2 d; } pk;
#pragma unroll
                for (int r = 0; r < 4; ++r)
                    pk.u[r] = f2bf(lrelu(accA[mt][nt][r] + gv[r]));
                *(uint2*)(y1cB + sw(n, m * 2)) = pk.d;
            }
        }
        __syncthreads();
#pragma unroll
        for (int nt = 0; nt < 2; ++nt) {
            const int n = nt * 16 + (l & 15);
#pragma unroll
            for (int ks = 0; ks < 8; ++ks) {
                bf16x8 Bf = *(const bf16x8*)(y1cB + sw(n, ks * 64 + (l >> 4) * 16));
#pragma unroll
                for (int mt = 0; mt < 4; ++mt)
                    accB[mt][nt] = __builtin_amdgcn_mfma_f32_16x16x32_bf16(
                        A2[mt][ks], Bf, accB[mt][nt], 0, 0, 0);
            }
        }
    }

    float p0 = 0.f, p1 = 0.f;
#pragma unroll
    for (int mt = 0; mt < 4; ++mt) {
        const int m = w * 64 + mt * 16 + ((l >> 4) << 2);
        const f32x4 bb = *(const f32x4*)(b2v + m);
        const f32x4 w3 = *(const f32x4*)(W3 + m);
#pragma unroll
        for (int r = 0; r < 4; ++r) {
            p0 = fmaf(w3[r], lrelu(accB[mt][0][r] + bb[r]), p0);
            p1 = fmaf(w3[r], lrelu(accB[mt][1][r] + bb[r]), p1);
        }
    }
    p0 += __shfl_xor(p0, 16); p0 += __shfl_xor(p0, 32);
    p1 += __shfl_xor(p1, 16); p1 += __shfl_xor(p1, 32);
    if (l < 16) { red[w][l] = p0; red[w][16 + l] = p1; }
    __syncthreads();
    if (t < 32) {
        float s = b3v[0] + red[0][t] + red[1][t] + red[2][t] + red[3][t];
        out[(size_t)b * N + n0 + t] = s;
    }
}

extern "C" void kernel_launch(void* const* d_in, const int* in_sizes, int n_in,
                              void* d_out, int out_size, void* d_ws, size_t ws_size,
                              hipStream_t stream) {
    const float* g     = (const float*)d_in[0];
    const float* pts   = (const float*)d_in[1];
    const float* lf    = (const float*)d_in[2];
    const float* W_ef1 = (const float*)d_in[3];
    const float* b_ef1 = (const float*)d_in[4];
    const float* W_ef2 = (const float*)d_in[5];
    const float* b_ef2 = (const float*)d_in[6];
    const float* W1    = (const float*)d_in[7];
    const float* b1    = (const float*)d_in[8];
    const float* W2    = (const float*)d_in[9];
    const float* b2    = (const float*)d_in[10];
    const float* W3    = (const float*)d_in[11];
    const float* b3    = (const float*)d_in[12];
    float* out = (float*)d_out;

    char* ws = (char*)d_ws;
    int*      idx   = (int*)ws;      ws += (size_t)B * N * KTOT * 4;
    float*    topd  = (float*)ws;
    float*    fmax_ws = (float*)topd;   // alias: topd dead before ef_mlp writes fmax
    ws += (size_t)B * NCHUNK * 16 * N * 4;
    float*    Tbuf  = (float*)ws;    ws += (size_t)B * N * 4;
    float*    gvec  = (float*)ws;    ws += (size_t)B * O1 * 4;
    unsigned short* W1p = (unsigned short*)ws; ws += (size_t)16 * 3 * 512 * 2;
    unsigned short* W2p = (unsigned short*)ws; ws += (size_t)8 * 8 * 512 * 2;
    unsigned short* W1m = (unsigned short*)ws; ws += (size_t)229376 * 2;
    unsigned short* W2m = (unsigned short*)ws; ws += (size_t)262144 * 2;

    prepack_w1<<<dim3(96), 256, 0, stream>>>(W_ef1, W1p);
    prepack_w2<<<dim3(128), 256, 0, stream>>>(W_ef2, W2p);
    prepack_mw1<<<dim3(896), 256, 0, stream>>>(W1, W1m);
    prepack_mw2<<<dim3(1024), 256, 0, stream>>>(W2, W2m);
    gvec_kernel<<<dim3(O1 / 256, B), 256, 0, stream>>>(W1, b1, g, gvec);
    knn_pass1<<<dim3(N / 256, NCHUNK, B), 256, 0, stream>>>(pts, topd);
    knn_thresh<<<dim3(N / 256, B), 256, 0, stream>>>(topd, Tbuf);
    knn_recover<<<dim3(N / 16, B), 256, 0, stream>>>(pts, Tbuf, idx);
    ef_mlp_mfma<<<dim3(N / 16, B), 256, 0, stream>>>(lf, pts, idx, W1p, b_ef1, W2p, b_ef2, fmax_ws);
    mlp_mfma<<<dim3(N / 32, B), 256, 0, stream>>>(lf, pts, fmax_ws, gvec, W1m, W2m, W3, b2, b3, out);
}